// Round 1
// baseline (1265.311 us; speedup 1.0000x reference)
//
#include <hip/hip_runtime.h>
#include <hip/hip_bf16.h>
#include <cstdint>
#include <cstddef>

// Problem constants (from reference)
#define NSRC   200000
#define NF     128
#define NHID   1500
#define NHIDP  1536     // padded hidden dim (multiple of 32 for MFMA K)
#define NCLS   64
#define E0N    1600000
#define E1N    500000
#define RES0   50000
#define RES1   10000

typedef __bf16 bf16x8 __attribute__((ext_vector_type(8)));
typedef float  f32x4  __attribute__((ext_vector_type(4)));
typedef unsigned short u16x8 __attribute__((ext_vector_type(8)));

__device__ __forceinline__ unsigned short f2bf(float f) {
    union { float f; unsigned u; } v; v.f = f;
    unsigned r = v.u + 0x7fffu + ((v.u >> 16) & 1u);   // RNE
    return (unsigned short)(r >> 16);
}

// ---------------- prep: build padded/transposed bf16 weights -----------------
// WcatT  [1536 n][256 k]  : rows 0..1499 = [W1_root; W1_neigh]^T, pad rows = 0
// W2catT [128  n][1536 k] : n<64 = W2_neigh^T, n>=64 = W2_root^T, pad k = 0
// b1e    [1536]           : b1 padded with zeros
__global__ void prep_kernel(const float* __restrict__ W1r, const float* __restrict__ W1n,
                            const float* __restrict__ b1,
                            const float* __restrict__ W2r, const float* __restrict__ W2n,
                            unsigned short* __restrict__ WcatT,
                            unsigned short* __restrict__ W2catT,
                            float* __restrict__ b1e) {
    int id = blockIdx.x * 256 + threadIdx.x;
    if (id < 256 * NHIDP) {
        int n = id >> 8, k = id & 255;
        float v = 0.f;
        if (n < NHID) v = (k < NF) ? W1r[k * NHID + n] : W1n[(k - NF) * NHID + n];
        WcatT[n * 256 + k] = f2bf(v);
    } else {
        int id2 = id - 256 * NHIDP;
        if (id2 < 128 * NHIDP) {
            int n = id2 / NHIDP, k = id2 % NHIDP;
            float v = 0.f;
            if (k < NHID) v = (n < 64) ? W2n[k * 64 + n] : W2r[k * 64 + (n - 64)];
            W2catT[n * NHIDP + k] = f2bf(v);
        } else {
            int c = id2 - 128 * NHIDP;
            if (c < NHIDP) b1e[c] = (c < NHID) ? b1[c] : 0.f;
        }
    }
}

// ---------------- aggregation layer 1 (atomics) ------------------------------
__global__ __launch_bounds__(256) void agg1_kernel(
        const float* __restrict__ x, const int* __restrict__ esrc,
        const int* __restrict__ etgt, float* __restrict__ sum1,
        unsigned int* __restrict__ cnt1) {
    int c = threadIdx.x & 127;
    int half = threadIdx.x >> 7;
    int ebase = blockIdx.x * 8;
#pragma unroll
    for (int i = 0; i < 4; ++i) {
        int e = ebase + i * 2 + half;
        int s = esrc[e], t = etgt[e];
        float v = x[(size_t)s * NF + c];
        atomicAdd(&sum1[(size_t)t * NF + c], v);
        if (c == 0) atomicAdd(&cnt1[t], 1u);
    }
}

__global__ void recip_kernel(const unsigned int* __restrict__ cnt1,
                             float* __restrict__ recip1) {
    int i = blockIdx.x * 256 + threadIdx.x;
    if (i < RES0) recip1[i] = 1.0f / fmaxf((float)cnt1[i], 1.0f);
}

// ---------------- GEMM1: h = relu([x[:50k]|mean] @ Wcat + b1) ---------------
// 128x128 tile, BK=32, 4 waves (2x2 of 64x64), mfma 16x16x32 bf16.
__global__ __launch_bounds__(256) void gemm1_kernel(
        const float* __restrict__ x, const float* __restrict__ sum1,
        const float* __restrict__ recip1, const unsigned short* __restrict__ WcatT,
        const float* __restrict__ b1e, unsigned short* __restrict__ h) {
    __shared__ __align__(16) unsigned short As[128 * 40];
    __shared__ __align__(16) unsigned short Bs[128 * 40];
    int m0 = blockIdx.x * 128;
    int n0 = blockIdx.y * 128;
    int tid = threadIdx.x;
    int lane = tid & 63, wid = tid >> 6;
    int wm = wid >> 1, wn = wid & 1;
    int quad = lane >> 4, l15 = lane & 15;

    f32x4 acc[4][4] = {};

    for (int kk = 0; kk < 256; kk += 32) {
        // stage A (convert fp32 -> bf16): 128 rows x 32 k, 8 elems/chunk
#pragma unroll
        for (int ci = 0; ci < 2; ++ci) {
            int cid = tid + ci * 256;
            int row = cid >> 2, k8 = (cid & 3) * 8;
            int gr = m0 + row; if (gr >= RES0) gr = RES0 - 1;
            int kg = kk + k8;
            float vals[8];
            if (kg < NF) {
                const float4* src = (const float4*)(x + (size_t)gr * NF + kg);
                float4 a = src[0], b = src[1];
                vals[0] = a.x; vals[1] = a.y; vals[2] = a.z; vals[3] = a.w;
                vals[4] = b.x; vals[5] = b.y; vals[6] = b.z; vals[7] = b.w;
            } else {
                const float4* src = (const float4*)(sum1 + (size_t)gr * NF + (kg - NF));
                float sc = recip1[gr];
                float4 a = src[0], b = src[1];
                vals[0] = a.x * sc; vals[1] = a.y * sc; vals[2] = a.z * sc; vals[3] = a.w * sc;
                vals[4] = b.x * sc; vals[5] = b.y * sc; vals[6] = b.z * sc; vals[7] = b.w * sc;
            }
            u16x8 o;
#pragma unroll
            for (int j = 0; j < 8; ++j) o[j] = f2bf(vals[j]);
            *(u16x8*)(&As[row * 40 + k8]) = o;
        }
        // stage B (already bf16, n-major so frags are contiguous along k)
#pragma unroll
        for (int ci = 0; ci < 2; ++ci) {
            int cid = tid + ci * 256;
            int n = cid >> 2, k8 = (cid & 3) * 8;
            u16x8 v = *(const u16x8*)(WcatT + (size_t)(n0 + n) * 256 + kk + k8);
            *(u16x8*)(&Bs[n * 40 + k8]) = v;
        }
        __syncthreads();
        bf16x8 a[4], b[4];
#pragma unroll
        for (int mi = 0; mi < 4; ++mi)
            a[mi] = *(const bf16x8*)(&As[(wm * 64 + mi * 16 + l15) * 40 + quad * 8]);
#pragma unroll
        for (int ni = 0; ni < 4; ++ni)
            b[ni] = *(const bf16x8*)(&Bs[(wn * 64 + ni * 16 + l15) * 40 + quad * 8]);
#pragma unroll
        for (int mi = 0; mi < 4; ++mi)
#pragma unroll
            for (int ni = 0; ni < 4; ++ni)
                acc[mi][ni] = __builtin_amdgcn_mfma_f32_16x16x32_bf16(a[mi], b[ni], acc[mi][ni], 0, 0, 0);
        __syncthreads();
    }

    // epilogue: + bias, relu, store bf16 (pad cols get relu(0+0)=0)
#pragma unroll
    for (int ni = 0; ni < 4; ++ni) {
        int gc = n0 + wn * 64 + ni * 16 + l15;
        float bv = b1e[gc];
#pragma unroll
        for (int mi = 0; mi < 4; ++mi) {
#pragma unroll
            for (int r = 0; r < 4; ++r) {
                int gr = m0 + wm * 64 + mi * 16 + quad * 4 + r;
                if (gr < RES0) {
                    float v = fmaxf(acc[mi][ni][r] + bv, 0.f);
                    h[(size_t)gr * NHIDP + gc] = f2bf(v);
                }
            }
        }
    }
}

// ---------------- GEMM2: p = h @ [W2_neigh | W2_root]  (50000 x 128) --------
// BM=64, BN=128, BK=32; 4 waves each own 16 rows x 128 cols.
__global__ __launch_bounds__(256) void gemm2_kernel(
        const unsigned short* __restrict__ h, const unsigned short* __restrict__ W2catT,
        float* __restrict__ p) {
    __shared__ __align__(16) unsigned short As[64 * 40];
    __shared__ __align__(16) unsigned short Bs[128 * 40];
    int m0 = blockIdx.x * 64;
    int tid = threadIdx.x, lane = tid & 63, wid = tid >> 6;
    int quad = lane >> 4, l15 = lane & 15;
    f32x4 acc[8] = {};

    for (int kk = 0; kk < NHIDP; kk += 32) {
        {   // A: 64x32 = 256 chunks of 8
            int row = tid >> 2, k8 = (tid & 3) * 8;
            int gr = m0 + row; if (gr >= RES0) gr = RES0 - 1;
            u16x8 v = *(const u16x8*)(h + (size_t)gr * NHIDP + kk + k8);
            *(u16x8*)(&As[row * 40 + k8]) = v;
        }
#pragma unroll
        for (int ci = 0; ci < 2; ++ci) {   // B: 128x32 = 512 chunks
            int cid = tid + ci * 256;
            int n = cid >> 2, k8 = (cid & 3) * 8;
            u16x8 v = *(const u16x8*)(W2catT + (size_t)n * NHIDP + kk + k8);
            *(u16x8*)(&Bs[n * 40 + k8]) = v;
        }
        __syncthreads();
        bf16x8 a = *(const bf16x8*)(&As[(wid * 16 + l15) * 40 + quad * 8]);
#pragma unroll
        for (int ni = 0; ni < 8; ++ni) {
            bf16x8 b = *(const bf16x8*)(&Bs[(ni * 16 + l15) * 40 + quad * 8]);
            acc[ni] = __builtin_amdgcn_mfma_f32_16x16x32_bf16(a, b, acc[ni], 0, 0, 0);
        }
        __syncthreads();
    }
#pragma unroll
    for (int ni = 0; ni < 8; ++ni) {
        int gc = ni * 16 + l15;
#pragma unroll
        for (int r = 0; r < 4; ++r) {
            int gr = m0 + wid * 16 + quad * 4 + r;
            if (gr < RES0) p[(size_t)gr * 128 + gc] = acc[ni][r];
        }
    }
}

// ---------------- aggregation layer 2 on projected features -----------------
__global__ __launch_bounds__(256) void agg2_kernel(
        const float* __restrict__ p, const int* __restrict__ esrc,
        const int* __restrict__ etgt, float* __restrict__ agg2,
        unsigned int* __restrict__ cnt2) {
    int c = threadIdx.x & 63;
    int q = threadIdx.x >> 6;
    int ebase = blockIdx.x * 8;
#pragma unroll
    for (int i = 0; i < 2; ++i) {
        int e = ebase + i * 4 + q;
        int s = esrc[e], t = etgt[e];
        float v = p[(size_t)s * 128 + c];   // neigh-projection columns 0..63
        atomicAdd(&agg2[t * 64 + c], v);
        if (c == 0) atomicAdd(&cnt2[t], 1u);
    }
}

// ---------------- final: root + mean_neigh + b2, log_softmax ----------------
__global__ __launch_bounds__(256) void final_kernel(
        const float* __restrict__ p, const float* __restrict__ agg2,
        const unsigned int* __restrict__ cnt2, const float* __restrict__ b2,
        float* __restrict__ out) {
    int c = threadIdx.x & 63;
    int rl = threadIdx.x >> 6;
    int row = blockIdx.x * 4 + rl;
    if (row >= RES1) return;
    float cf = fmaxf((float)cnt2[row], 1.0f);
    float v = p[(size_t)row * 128 + 64 + c] + agg2[row * 64 + c] / cf + b2[c];
    float m = v;
#pragma unroll
    for (int off = 32; off > 0; off >>= 1) m = fmaxf(m, __shfl_xor(m, off, 64));
    float ex = expf(v - m);
    float s = ex;
#pragma unroll
    for (int off = 32; off > 0; off >>= 1) s += __shfl_xor(s, off, 64);
    out[(size_t)row * 64 + c] = v - m - logf(s);
}

extern "C" void kernel_launch(void* const* d_in, const int* in_sizes, int n_in,
                              void* d_out, int out_size, void* d_ws, size_t ws_size,
                              hipStream_t stream) {
    const float* x   = (const float*)d_in[0];
    const float* W1r = (const float*)d_in[1];
    const float* W1n = (const float*)d_in[2];
    const float* b1  = (const float*)d_in[3];
    const float* W2r = (const float*)d_in[4];
    const float* W2n = (const float*)d_in[5];
    const float* b2  = (const float*)d_in[6];
    const int* es0 = (const int*)d_in[7];
    const int* et0 = (const int*)d_in[8];
    const int* es1 = (const int*)d_in[9];
    const int* et1 = (const int*)d_in[10];
    float* out = (float*)d_out;

    char* ws = (char*)d_ws;
    size_t off = 0;
    auto alloc = [&](size_t bytes) {
        void* ptr = ws + off;
        off = (off + bytes + 255) & ~(size_t)255;
        return ptr;
    };
    float*          sum1   = (float*)alloc((size_t)RES0 * NF * 4);
    unsigned int*   cnt1   = (unsigned int*)alloc((size_t)RES0 * 4);
    float*          agg2   = (float*)alloc((size_t)RES1 * 64 * 4);
    unsigned int*   cnt2   = (unsigned int*)alloc((size_t)RES1 * 4);
    size_t zero_bytes = off;
    float*          recip1 = (float*)alloc((size_t)RES0 * 4);
    unsigned short* WcatT  = (unsigned short*)alloc((size_t)NHIDP * 256 * 2);
    unsigned short* W2catT = (unsigned short*)alloc((size_t)128 * NHIDP * 2);
    float*          b1e    = (float*)alloc((size_t)NHIDP * 4);
    unsigned short* h      = (unsigned short*)alloc((size_t)RES0 * NHIDP * 2);
    float*          p      = (float*)alloc((size_t)RES0 * 128 * 4);

    hipMemsetAsync(d_ws, 0, zero_bytes, stream);

    prep_kernel<<<(256 * NHIDP + 128 * NHIDP + NHIDP + 255) / 256, 256, 0, stream>>>(
        W1r, W1n, b1, W2r, W2n, WcatT, W2catT, b1e);

    agg1_kernel<<<E0N / 8, 256, 0, stream>>>(x, es0, et0, sum1, cnt1);
    recip_kernel<<<(RES0 + 255) / 256, 256, 0, stream>>>(cnt1, recip1);

    gemm1_kernel<<<dim3((RES0 + 127) / 128, NHIDP / 128), 256, 0, stream>>>(
        x, sum1, recip1, WcatT, b1e, h);

    gemm2_kernel<<<(RES0 + 63) / 64, 256, 0, stream>>>(h, W2catT, p);

    agg2_kernel<<<E1N / 8, 256, 0, stream>>>(p, es1, et1, agg2, cnt2);

    final_kernel<<<RES1 / 4, 256, 0, stream>>>(p, agg2, cnt2, b2, out);
}

// Round 2
// 912.599 us; speedup vs baseline: 1.3865x; 1.3865x over previous
//
#include <hip/hip_runtime.h>
#include <hip/hip_bf16.h>
#include <cstdint>
#include <cstddef>

// Problem constants (from reference)
#define NSRC   200000
#define NF     128
#define NHID   1500
#define NHIDP  1536     // padded hidden dim (multiple of 32 for MFMA K)
#define NCLS   64
#define E0N    1600000
#define E1N    500000
#define RES0   50000
#define RES1   10000

typedef __bf16 bf16x8 __attribute__((ext_vector_type(8)));
typedef float  f32x4  __attribute__((ext_vector_type(4)));
typedef unsigned short u16x8 __attribute__((ext_vector_type(8)));
typedef unsigned int u32;

__device__ __forceinline__ unsigned short f2bf(float f) {
    union { float f; unsigned u; } v; v.f = f;
    unsigned r = v.u + 0x7fffu + ((v.u >> 16) & 1u);   // RNE
    return (unsigned short)(r >> 16);
}

// ---------------- prep: build padded/transposed bf16 weights -----------------
__global__ void prep_kernel(const float* __restrict__ W1r, const float* __restrict__ W1n,
                            const float* __restrict__ b1,
                            const float* __restrict__ W2r, const float* __restrict__ W2n,
                            unsigned short* __restrict__ WcatT,
                            unsigned short* __restrict__ W2catT,
                            float* __restrict__ b1e) {
    int id = blockIdx.x * 256 + threadIdx.x;
    if (id < 256 * NHIDP) {
        int n = id >> 8, k = id & 255;
        float v = 0.f;
        if (n < NHID) v = (k < NF) ? W1r[k * NHID + n] : W1n[(k - NF) * NHID + n];
        WcatT[n * 256 + k] = f2bf(v);
    } else {
        int id2 = id - 256 * NHIDP;
        if (id2 < 128 * NHIDP) {
            int n = id2 / NHIDP, k = id2 % NHIDP;
            float v = 0.f;
            if (k < NHID) v = (n < 64) ? W2n[k * 64 + n] : W2r[k * 64 + (n - 64)];
            W2catT[n * NHIDP + k] = f2bf(v);
        } else {
            int c = id2 - 128 * NHIDP;
            if (c < NHIDP) b1e[c] = (c < NHID) ? b1[c] : 0.f;
        }
    }
}

// ---------------- CSR build: histogram, scan, scatter ------------------------
__global__ void hist_kernel(const int* __restrict__ tgt, int n, u32* __restrict__ cnt) {
    int i = blockIdx.x * 256 + threadIdx.x;
    if (i < n) atomicAdd(&cnt[tgt[i]], 1u);
}

// single-block exclusive scan; writes off[] and a working copy cur[]
__global__ __launch_bounds__(1024) void scan_kernel(const u32* __restrict__ cnt,
                                                    u32* __restrict__ off,
                                                    u32* __restrict__ cur, int n) {
    __shared__ u32 part[1024];
    int t = threadIdx.x;
    int chunk = (n + 1023) / 1024;
    int s = t * chunk, e = min(s + chunk, n);
    u32 sum = 0;
    for (int i = s; i < e; ++i) sum += cnt[i];
    part[t] = sum;
    __syncthreads();
    for (int d = 1; d < 1024; d <<= 1) {
        u32 v = part[t];
        u32 add = (t >= d) ? part[t - d] : 0u;
        __syncthreads();
        part[t] = v + add;
        __syncthreads();
    }
    u32 run = (t == 0) ? 0u : part[t - 1];
    for (int i = s; i < e; ++i) {
        off[i] = run; cur[i] = run;
        run += cnt[i];
    }
}

__global__ void scatter_kernel(const int* __restrict__ src, const int* __restrict__ tgt,
                               int n, u32* __restrict__ cur, int* __restrict__ csr) {
    int i = blockIdx.x * 256 + threadIdx.x;
    if (i < n) {
        u32 pos = atomicAdd(&cur[tgt[i]], 1u);
        csr[pos] = src[i];
    }
}

// ---------------- layer-1 mean aggregation via CSR (no float atomics) --------
// one block (128 threads = 128 columns) per target row; writes bf16 mean
__global__ __launch_bounds__(128) void agg1_csr_kernel(
        const float* __restrict__ x, const int* __restrict__ csr,
        const u32* __restrict__ off, const u32* __restrict__ cnt,
        unsigned short* __restrict__ mean1) {
    int row = blockIdx.x;
    int c = threadIdx.x;
    u32 base = off[row], deg = cnt[row];
    float a0 = 0.f, a1 = 0.f, a2 = 0.f, a3 = 0.f;
    u32 e = 0;
    for (; e + 4 <= deg; e += 4) {
        int s0 = csr[base + e], s1 = csr[base + e + 1];
        int s2 = csr[base + e + 2], s3 = csr[base + e + 3];
        a0 += x[(size_t)s0 * NF + c];
        a1 += x[(size_t)s1 * NF + c];
        a2 += x[(size_t)s2 * NF + c];
        a3 += x[(size_t)s3 * NF + c];
    }
    for (; e < deg; ++e) a0 += x[(size_t)csr[base + e] * NF + c];
    float m = ((a0 + a1) + (a2 + a3)) / fmaxf((float)deg, 1.0f);
    mean1[(size_t)row * NF + c] = f2bf(m);
}

// ---------------- GEMM1: h = relu([x[:50k]|mean1] @ Wcat + b1) ---------------
__global__ __launch_bounds__(256) void gemm1_kernel(
        const float* __restrict__ x, const unsigned short* __restrict__ mean1,
        const unsigned short* __restrict__ WcatT,
        const float* __restrict__ b1e, unsigned short* __restrict__ h) {
    __shared__ __align__(16) unsigned short As[128 * 40];
    __shared__ __align__(16) unsigned short Bs[128 * 40];
    int m0 = blockIdx.x * 128;
    int n0 = blockIdx.y * 128;
    int tid = threadIdx.x;
    int lane = tid & 63, wid = tid >> 6;
    int wm = wid >> 1, wn = wid & 1;
    int quad = lane >> 4, l15 = lane & 15;

    f32x4 acc[4][4] = {};

    for (int kk = 0; kk < 256; kk += 32) {
#pragma unroll
        for (int ci = 0; ci < 2; ++ci) {
            int cid = tid + ci * 256;
            int row = cid >> 2, k8 = (cid & 3) * 8;
            int gr = m0 + row; if (gr >= RES0) gr = RES0 - 1;
            int kg = kk + k8;
            if (kg < NF) {
                const float4* src = (const float4*)(x + (size_t)gr * NF + kg);
                float4 a = src[0], b = src[1];
                u16x8 o;
                o[0] = f2bf(a.x); o[1] = f2bf(a.y); o[2] = f2bf(a.z); o[3] = f2bf(a.w);
                o[4] = f2bf(b.x); o[5] = f2bf(b.y); o[6] = f2bf(b.z); o[7] = f2bf(b.w);
                *(u16x8*)(&As[row * 40 + k8]) = o;
            } else {
                u16x8 v = *(const u16x8*)(mean1 + (size_t)gr * NF + (kg - NF));
                *(u16x8*)(&As[row * 40 + k8]) = v;
            }
        }
#pragma unroll
        for (int ci = 0; ci < 2; ++ci) {
            int cid = tid + ci * 256;
            int n = cid >> 2, k8 = (cid & 3) * 8;
            u16x8 v = *(const u16x8*)(WcatT + (size_t)(n0 + n) * 256 + kk + k8);
            *(u16x8*)(&Bs[n * 40 + k8]) = v;
        }
        __syncthreads();
        bf16x8 a[4], b[4];
#pragma unroll
        for (int mi = 0; mi < 4; ++mi)
            a[mi] = *(const bf16x8*)(&As[(wm * 64 + mi * 16 + l15) * 40 + quad * 8]);
#pragma unroll
        for (int ni = 0; ni < 4; ++ni)
            b[ni] = *(const bf16x8*)(&Bs[(wn * 64 + ni * 16 + l15) * 40 + quad * 8]);
#pragma unroll
        for (int mi = 0; mi < 4; ++mi)
#pragma unroll
            for (int ni = 0; ni < 4; ++ni)
                acc[mi][ni] = __builtin_amdgcn_mfma_f32_16x16x32_bf16(a[mi], b[ni], acc[mi][ni], 0, 0, 0);
        __syncthreads();
    }

#pragma unroll
    for (int ni = 0; ni < 4; ++ni) {
        int gc = n0 + wn * 64 + ni * 16 + l15;
        float bv = b1e[gc];
#pragma unroll
        for (int mi = 0; mi < 4; ++mi) {
#pragma unroll
            for (int r = 0; r < 4; ++r) {
                int gr = m0 + wm * 64 + mi * 16 + quad * 4 + r;
                if (gr < RES0) {
                    float v = fmaxf(acc[mi][ni][r] + bv, 0.f);
                    h[(size_t)gr * NHIDP + gc] = f2bf(v);
                }
            }
        }
    }
}

// ---------------- GEMM2: p = h @ [W2_neigh | W2_root]  (50000 x 128) --------
__global__ __launch_bounds__(256) void gemm2_kernel(
        const unsigned short* __restrict__ h, const unsigned short* __restrict__ W2catT,
        float* __restrict__ p) {
    __shared__ __align__(16) unsigned short As[64 * 40];
    __shared__ __align__(16) unsigned short Bs[128 * 40];
    int m0 = blockIdx.x * 64;
    int tid = threadIdx.x, lane = tid & 63, wid = tid >> 6;
    int quad = lane >> 4, l15 = lane & 15;
    f32x4 acc[8] = {};

    for (int kk = 0; kk < NHIDP; kk += 32) {
        {
            int row = tid >> 2, k8 = (tid & 3) * 8;
            int gr = m0 + row; if (gr >= RES0) gr = RES0 - 1;
            u16x8 v = *(const u16x8*)(h + (size_t)gr * NHIDP + kk + k8);
            *(u16x8*)(&As[row * 40 + k8]) = v;
        }
#pragma unroll
        for (int ci = 0; ci < 2; ++ci) {
            int cid = tid + ci * 256;
            int n = cid >> 2, k8 = (cid & 3) * 8;
            u16x8 v = *(const u16x8*)(W2catT + (size_t)n * NHIDP + kk + k8);
            *(u16x8*)(&Bs[n * 40 + k8]) = v;
        }
        __syncthreads();
        bf16x8 a = *(const bf16x8*)(&As[(wid * 16 + l15) * 40 + quad * 8]);
#pragma unroll
        for (int ni = 0; ni < 8; ++ni) {
            bf16x8 b = *(const bf16x8*)(&Bs[(ni * 16 + l15) * 40 + quad * 8]);
            acc[ni] = __builtin_amdgcn_mfma_f32_16x16x32_bf16(a, b, acc[ni], 0, 0, 0);
        }
        __syncthreads();
    }
#pragma unroll
    for (int ni = 0; ni < 8; ++ni) {
        int gc = ni * 16 + l15;
#pragma unroll
        for (int r = 0; r < 4; ++r) {
            int gr = m0 + wid * 16 + quad * 4 + r;
            if (gr < RES0) p[(size_t)gr * 128 + gc] = acc[ni][r];
        }
    }
}

// ---------------- fused layer-2 aggregation + log_softmax (CSR) --------------
// one wave per target row; lane = class column
__global__ __launch_bounds__(64) void final_csr_kernel(
        const float* __restrict__ p, const int* __restrict__ csr,
        const u32* __restrict__ off, const u32* __restrict__ cnt,
        const float* __restrict__ b2, float* __restrict__ out) {
    int row = blockIdx.x;
    int c = threadIdx.x;
    u32 base = off[row], deg = cnt[row];
    float a0 = 0.f, a1 = 0.f, a2 = 0.f, a3 = 0.f;
    u32 e = 0;
    for (; e + 4 <= deg; e += 4) {
        int s0 = csr[base + e], s1 = csr[base + e + 1];
        int s2 = csr[base + e + 2], s3 = csr[base + e + 3];
        a0 += p[(size_t)s0 * 128 + c];
        a1 += p[(size_t)s1 * 128 + c];
        a2 += p[(size_t)s2 * 128 + c];
        a3 += p[(size_t)s3 * 128 + c];
    }
    for (; e < deg; ++e) a0 += p[(size_t)csr[base + e] * 128 + c];
    float mean = ((a0 + a1) + (a2 + a3)) / fmaxf((float)deg, 1.0f);
    float v = p[(size_t)row * 128 + 64 + c] + mean + b2[c];
    float m = v;
#pragma unroll
    for (int o = 32; o > 0; o >>= 1) m = fmaxf(m, __shfl_xor(m, o, 64));
    float ex = expf(v - m);
    float s = ex;
#pragma unroll
    for (int o = 32; o > 0; o >>= 1) s += __shfl_xor(s, o, 64);
    out[(size_t)row * 64 + c] = v - m - logf(s);
}

extern "C" void kernel_launch(void* const* d_in, const int* in_sizes, int n_in,
                              void* d_out, int out_size, void* d_ws, size_t ws_size,
                              hipStream_t stream) {
    const float* x   = (const float*)d_in[0];
    const float* W1r = (const float*)d_in[1];
    const float* W1n = (const float*)d_in[2];
    const float* b1  = (const float*)d_in[3];
    const float* W2r = (const float*)d_in[4];
    const float* W2n = (const float*)d_in[5];
    const float* b2  = (const float*)d_in[6];
    const int* es0 = (const int*)d_in[7];
    const int* et0 = (const int*)d_in[8];
    const int* es1 = (const int*)d_in[9];
    const int* et1 = (const int*)d_in[10];
    float* out = (float*)d_out;

    char* ws = (char*)d_ws;
    size_t off = 0;
    auto alloc = [&](size_t bytes) {
        void* ptr = ws + off;
        off = (off + bytes + 255) & ~(size_t)255;
        return ptr;
    };
    // zeroed region first (histograms only)
    u32* cnt1 = (u32*)alloc((size_t)RES0 * 4);
    u32* cnt2 = (u32*)alloc((size_t)RES1 * 4);
    size_t zero_bytes = off;
    u32* off1 = (u32*)alloc((size_t)RES0 * 4);
    u32* cur1 = (u32*)alloc((size_t)RES0 * 4);
    int* csr1 = (int*)alloc((size_t)E0N * 4);
    u32* off2 = (u32*)alloc((size_t)RES1 * 4);
    u32* cur2 = (u32*)alloc((size_t)RES1 * 4);
    int* csr2 = (int*)alloc((size_t)E1N * 4);
    unsigned short* mean1  = (unsigned short*)alloc((size_t)RES0 * NF * 2);
    unsigned short* WcatT  = (unsigned short*)alloc((size_t)NHIDP * 256 * 2);
    unsigned short* W2catT = (unsigned short*)alloc((size_t)128 * NHIDP * 2);
    float*          b1e    = (float*)alloc((size_t)NHIDP * 4);
    unsigned short* h      = (unsigned short*)alloc((size_t)RES0 * NHIDP * 2);
    float*          p      = (float*)alloc((size_t)RES0 * 128 * 4);

    hipMemsetAsync(d_ws, 0, zero_bytes, stream);

    prep_kernel<<<(256 * NHIDP + 128 * NHIDP + NHIDP + 255) / 256, 256, 0, stream>>>(
        W1r, W1n, b1, W2r, W2n, WcatT, W2catT, b1e);

    // CSR build for both graphs
    hist_kernel<<<(E0N + 255) / 256, 256, 0, stream>>>(et0, E0N, cnt1);
    hist_kernel<<<(E1N + 255) / 256, 256, 0, stream>>>(et1, E1N, cnt2);
    scan_kernel<<<1, 1024, 0, stream>>>(cnt1, off1, cur1, RES0);
    scan_kernel<<<1, 1024, 0, stream>>>(cnt2, off2, cur2, RES1);
    scatter_kernel<<<(E0N + 255) / 256, 256, 0, stream>>>(es0, et0, E0N, cur1, csr1);
    scatter_kernel<<<(E1N + 255) / 256, 256, 0, stream>>>(es1, et1, E1N, cur2, csr2);

    agg1_csr_kernel<<<RES0, 128, 0, stream>>>(x, csr1, off1, cnt1, mean1);

    gemm1_kernel<<<dim3((RES0 + 127) / 128, NHIDP / 128), 256, 0, stream>>>(
        x, mean1, WcatT, b1e, h);

    gemm2_kernel<<<(RES0 + 63) / 64, 256, 0, stream>>>(h, W2catT, p);

    final_csr_kernel<<<RES1, 64, 0, stream>>>(p, csr2, off2, cnt2, b2, out);
}

// Round 3
// 791.650 us; speedup vs baseline: 1.5983x; 1.1528x over previous
//
#include <hip/hip_runtime.h>
#include <hip/hip_bf16.h>
#include <cstdint>
#include <cstddef>

// Problem constants (from reference)
#define NSRC   200000
#define NF     128
#define NHID   1500
#define NHIDP  1536     // padded hidden dim (multiple of 128)
#define NCLS   64
#define E0N    1600000
#define E1N    500000
#define RES0   50000
#define RES1   10000

typedef __bf16 bf16x8 __attribute__((ext_vector_type(8)));
typedef float  f32x4  __attribute__((ext_vector_type(4)));
typedef unsigned short u16x8 __attribute__((ext_vector_type(8)));
typedef unsigned int u32;

__device__ __forceinline__ unsigned short f2bf(float f) {
    union { float f; unsigned u; } v; v.f = f;
    unsigned r = v.u + 0x7fffu + ((v.u >> 16) & 1u);   // RNE
    return (unsigned short)(r >> 16);
}
__device__ __forceinline__ float bf2f(unsigned short b) {
    union { unsigned u; float f; } v; v.u = ((unsigned)b) << 16;
    return v.f;
}

// async 16B global -> LDS DMA (dest = wave-uniform lds base + lane*16)
__device__ __forceinline__ void lds_dma16(const void* g, void* lds) {
    __builtin_amdgcn_global_load_lds(
        (const __attribute__((address_space(1))) unsigned int*)g,
        (__attribute__((address_space(3))) unsigned int*)lds, 16, 0, 0);
}

// ---------------- prep: padded/transposed bf16 weights -----------------------
// WcatT  [1536 n][256 k]  rows>=1500 zero;  W2catT [128 n][1536 k] k>=1500 zero
__global__ void prep_kernel(const float* __restrict__ W1r, const float* __restrict__ W1n,
                            const float* __restrict__ b1,
                            const float* __restrict__ W2r, const float* __restrict__ W2n,
                            unsigned short* __restrict__ WcatT,
                            unsigned short* __restrict__ W2catT,
                            float* __restrict__ b1e) {
    int id = blockIdx.x * 256 + threadIdx.x;
    if (id < 256 * NHIDP) {
        int n = id >> 8, k = id & 255;
        float v = 0.f;
        if (n < NHID) v = (k < NF) ? W1r[k * NHID + n] : W1n[(k - NF) * NHID + n];
        WcatT[n * 256 + k] = f2bf(v);
    } else {
        int id2 = id - 256 * NHIDP;
        if (id2 < 128 * NHIDP) {
            int n = id2 / NHIDP, k = id2 % NHIDP;
            float v = 0.f;
            if (k < NHID) v = (n < 64) ? W2n[k * 64 + n] : W2r[k * 64 + (n - 64)];
            W2catT[n * NHIDP + k] = f2bf(v);
        } else {
            int c = id2 - 128 * NHIDP;
            if (c < NHIDP) b1e[c] = (c < NHID) ? b1[c] : 0.f;
        }
    }
}

// ---------------- x -> bf16 copy (full 200000 x 128) -------------------------
__global__ __launch_bounds__(256) void copyx_kernel(const float* __restrict__ x,
                                                    unsigned short* __restrict__ xbf) {
    size_t i = ((size_t)blockIdx.x * 256 + threadIdx.x) * 8;
    const float4* s = (const float4*)(x + i);
    float4 a = s[0], b = s[1];
    u16x8 o;
    o[0] = f2bf(a.x); o[1] = f2bf(a.y); o[2] = f2bf(a.z); o[3] = f2bf(a.w);
    o[4] = f2bf(b.x); o[5] = f2bf(b.y); o[6] = f2bf(b.z); o[7] = f2bf(b.w);
    *(u16x8*)(xbf + i) = o;
}

// ---------------- CSR build --------------------------------------------------
__global__ void hist_kernel(const int* __restrict__ tgt, int n, u32* __restrict__ cnt) {
    int i = blockIdx.x * 256 + threadIdx.x;
    if (i < n) atomicAdd(&cnt[tgt[i]], 1u);
}

__global__ __launch_bounds__(1024) void scan_kernel(const u32* __restrict__ cnt,
                                                    u32* __restrict__ off,
                                                    u32* __restrict__ cur, int n) {
    __shared__ u32 part[1024];
    int t = threadIdx.x;
    int chunk = (n + 1023) / 1024;
    int s = t * chunk, e = min(s + chunk, n);
    u32 sum = 0;
    for (int i = s; i < e; ++i) sum += cnt[i];
    part[t] = sum;
    __syncthreads();
    for (int d = 1; d < 1024; d <<= 1) {
        u32 v = part[t];
        u32 add = (t >= d) ? part[t - d] : 0u;
        __syncthreads();
        part[t] = v + add;
        __syncthreads();
    }
    u32 run = (t == 0) ? 0u : part[t - 1];
    for (int i = s; i < e; ++i) {
        off[i] = run; cur[i] = run;
        run += cnt[i];
    }
}

__global__ void scatter_kernel(const int* __restrict__ src, const int* __restrict__ tgt,
                               int n, u32* __restrict__ cur, int* __restrict__ csr) {
    int i = blockIdx.x * 256 + threadIdx.x;
    if (i < n) {
        u32 pos = atomicAdd(&cur[tgt[i]], 1u);
        csr[pos] = src[i];
    }
}

// ---------------- layer-1 mean aggregation (bf16 gathers) --------------------
__global__ __launch_bounds__(128) void agg1_csr_kernel(
        const unsigned short* __restrict__ xbf, const int* __restrict__ csr,
        const u32* __restrict__ off, const u32* __restrict__ cnt,
        unsigned short* __restrict__ mean1) {
    int row = blockIdx.x;
    int c = threadIdx.x;
    u32 base = off[row], deg = cnt[row];
    float a0 = 0.f, a1 = 0.f, a2 = 0.f, a3 = 0.f;
    u32 e = 0;
    for (; e + 4 <= deg; e += 4) {
        int s0 = csr[base + e], s1 = csr[base + e + 1];
        int s2 = csr[base + e + 2], s3 = csr[base + e + 3];
        a0 += bf2f(xbf[(size_t)s0 * NF + c]);
        a1 += bf2f(xbf[(size_t)s1 * NF + c]);
        a2 += bf2f(xbf[(size_t)s2 * NF + c]);
        a3 += bf2f(xbf[(size_t)s3 * NF + c]);
    }
    for (; e < deg; ++e) a0 += bf2f(xbf[(size_t)csr[base + e] * NF + c]);
    float m = ((a0 + a1) + (a2 + a3)) / fmaxf((float)deg, 1.0f);
    mean1[(size_t)row * NF + c] = f2bf(m);
}

// ---------------- fused GEMM: p = relu([xbf|mean1]@Wcat + b1) @ W2cat --------
// per block: 128 rows of p (128 cols). 12 j-chunks of 128 hidden cols.
// stage1: K=256 via LDS-DMA'd A/B kbufs; stage2: K=128 via htile LDS round-trip.
__global__ __launch_bounds__(256, 2) void fused_gemm_kernel(
        const unsigned short* __restrict__ xbf, const unsigned short* __restrict__ mean1,
        const unsigned short* __restrict__ WcatT, const float* __restrict__ b1e,
        const unsigned short* __restrict__ W2catT, float* __restrict__ p) {
    __shared__ __align__(16) unsigned short As[128 * 32];
    __shared__ __align__(16) unsigned short Bs[128 * 32];
    __shared__ __align__(16) unsigned short Ht[128 * 136];

    int m0 = blockIdx.x * 128;
    int tid = threadIdx.x;
    int lane = tid & 63, wid = tid >> 6;
    int wm = wid >> 1, wn = wid & 1;
    int quad = lane >> 4, l15 = lane & 15;

    f32x4 pacc[4][4] = {};

    for (int j = 0; j < 12; ++j) {
        f32x4 hacc[4][4] = {};
        // ---- stage 1: hacc = A(128x256) @ Wcat_j(256x128) ----
        for (int kk = 0; kk < 256; kk += 32) {
#pragma unroll
            for (int ci = 0; ci < 2; ++ci) {
                int cb = ci * 256 + wid * 64;          // wave-uniform chunk base
                int chunk = cb + lane;
                int n = chunk >> 2, kc = chunk & 3;
                const unsigned short* g = (kk < 128)
                    ? xbf + (size_t)(m0 + n) * NF + kk + kc * 8
                    : mean1 + (size_t)(m0 + n) * NF + (kk - 128) + kc * 8;
                lds_dma16(g, &As[cb * 8]);
            }
#pragma unroll
            for (int ci = 0; ci < 2; ++ci) {
                int cb = ci * 256 + wid * 64;
                int chunk = cb + lane;
                int n = chunk >> 2, kc = chunk & 3;
                const unsigned short* g = WcatT + (size_t)(j * 128 + n) * 256 + kk + kc * 8;
                lds_dma16(g, &Bs[cb * 8]);
            }
            __syncthreads();
            bf16x8 a[4], b[4];
#pragma unroll
            for (int mi = 0; mi < 4; ++mi)
                a[mi] = *(const bf16x8*)(&As[(wm * 64 + mi * 16 + l15) * 32 + quad * 8]);
#pragma unroll
            for (int ni = 0; ni < 4; ++ni)
                b[ni] = *(const bf16x8*)(&Bs[(wn * 64 + ni * 16 + l15) * 32 + quad * 8]);
#pragma unroll
            for (int mi = 0; mi < 4; ++mi)
#pragma unroll
                for (int ni = 0; ni < 4; ++ni)
                    hacc[mi][ni] = __builtin_amdgcn_mfma_f32_16x16x32_bf16(a[mi], b[ni], hacc[mi][ni], 0, 0, 0);
            __syncthreads();
        }
        // ---- epilogue 1: bias + relu -> bf16 -> Ht (C-layout -> [m][k]) ----
#pragma unroll
        for (int ni = 0; ni < 4; ++ni) {
            int lc = wn * 64 + ni * 16 + l15;
            float bv = b1e[j * 128 + lc];
#pragma unroll
            for (int mi = 0; mi < 4; ++mi) {
#pragma unroll
                for (int r = 0; r < 4; ++r) {
                    int row = wm * 64 + mi * 16 + quad * 4 + r;
                    Ht[row * 136 + lc] = f2bf(fmaxf(hacc[mi][ni][r] + bv, 0.f));
                }
            }
        }
        __syncthreads();
        // ---- stage 2: pacc += Ht(128x128) @ W2cat_j(128x128) ----
#pragma unroll
        for (int kk2 = 0; kk2 < 128; kk2 += 32) {
            bf16x8 a2[4], b2[4];
#pragma unroll
            for (int mi = 0; mi < 4; ++mi)
                a2[mi] = *(const bf16x8*)(&Ht[(wm * 64 + mi * 16 + l15) * 136 + kk2 + quad * 8]);
#pragma unroll
            for (int ni = 0; ni < 4; ++ni)
                b2[ni] = *(const bf16x8*)(W2catT + (size_t)(wn * 64 + ni * 16 + l15) * NHIDP
                                          + j * 128 + kk2 + quad * 8);
#pragma unroll
            for (int mi = 0; mi < 4; ++mi)
#pragma unroll
                for (int ni = 0; ni < 4; ++ni)
                    pacc[mi][ni] = __builtin_amdgcn_mfma_f32_16x16x32_bf16(a2[mi], b2[ni], pacc[mi][ni], 0, 0, 0);
        }
        __syncthreads();   // protect Ht before next j overwrites
    }

    // ---- write p (fp32) ----
#pragma unroll
    for (int ni = 0; ni < 4; ++ni) {
        int gc = wn * 64 + ni * 16 + l15;
#pragma unroll
        for (int mi = 0; mi < 4; ++mi) {
#pragma unroll
            for (int r = 0; r < 4; ++r) {
                int gr = m0 + wm * 64 + mi * 16 + quad * 4 + r;
                if (gr < RES0) p[(size_t)gr * 128 + gc] = pacc[mi][ni][r];
            }
        }
    }
}

// ---------------- fused layer-2 aggregation + log_softmax --------------------
__global__ __launch_bounds__(64) void final_csr_kernel(
        const float* __restrict__ p, const int* __restrict__ csr,
        const u32* __restrict__ off, const u32* __restrict__ cnt,
        const float* __restrict__ b2, float* __restrict__ out) {
    int row = blockIdx.x;
    int c = threadIdx.x;
    u32 base = off[row], deg = cnt[row];
    float a0 = 0.f, a1 = 0.f, a2 = 0.f, a3 = 0.f;
    u32 e = 0;
    for (; e + 4 <= deg; e += 4) {
        int s0 = csr[base + e], s1 = csr[base + e + 1];
        int s2 = csr[base + e + 2], s3 = csr[base + e + 3];
        a0 += p[(size_t)s0 * 128 + c];
        a1 += p[(size_t)s1 * 128 + c];
        a2 += p[(size_t)s2 * 128 + c];
        a3 += p[(size_t)s3 * 128 + c];
    }
    for (; e < deg; ++e) a0 += p[(size_t)csr[base + e] * 128 + c];
    float mean = ((a0 + a1) + (a2 + a3)) / fmaxf((float)deg, 1.0f);
    float v = p[(size_t)row * 128 + 64 + c] + mean + b2[c];
    float m = v;
#pragma unroll
    for (int o = 32; o > 0; o >>= 1) m = fmaxf(m, __shfl_xor(m, o, 64));
    float ex = expf(v - m);
    float s = ex;
#pragma unroll
    for (int o = 32; o > 0; o >>= 1) s += __shfl_xor(s, o, 64);
    out[(size_t)row * 64 + c] = v - m - logf(s);
}

extern "C" void kernel_launch(void* const* d_in, const int* in_sizes, int n_in,
                              void* d_out, int out_size, void* d_ws, size_t ws_size,
                              hipStream_t stream) {
    const float* x   = (const float*)d_in[0];
    const float* W1r = (const float*)d_in[1];
    const float* W1n = (const float*)d_in[2];
    const float* b1  = (const float*)d_in[3];
    const float* W2r = (const float*)d_in[4];
    const float* W2n = (const float*)d_in[5];
    const float* b2  = (const float*)d_in[6];
    const int* es0 = (const int*)d_in[7];
    const int* et0 = (const int*)d_in[8];
    const int* es1 = (const int*)d_in[9];
    const int* et1 = (const int*)d_in[10];
    float* out = (float*)d_out;

    char* ws = (char*)d_ws;
    size_t off = 0;
    auto alloc = [&](size_t bytes) {
        void* ptr = ws + off;
        off = (off + bytes + 255) & ~(size_t)255;
        return ptr;
    };
    u32* cnt1 = (u32*)alloc((size_t)RES0 * 4);
    u32* cnt2 = (u32*)alloc((size_t)RES1 * 4);
    size_t zero_bytes = off;
    u32* off1 = (u32*)alloc((size_t)RES0 * 4);
    u32* cur1 = (u32*)alloc((size_t)RES0 * 4);
    int* csr1 = (int*)alloc((size_t)E0N * 4);
    u32* off2 = (u32*)alloc((size_t)RES1 * 4);
    u32* cur2 = (u32*)alloc((size_t)RES1 * 4);
    int* csr2 = (int*)alloc((size_t)E1N * 4);
    unsigned short* xbf    = (unsigned short*)alloc((size_t)NSRC * NF * 2);
    unsigned short* mean1  = (unsigned short*)alloc((size_t)(RES0 + 128) * NF * 2); // padded rows
    unsigned short* WcatT  = (unsigned short*)alloc((size_t)NHIDP * 256 * 2);
    unsigned short* W2catT = (unsigned short*)alloc((size_t)128 * NHIDP * 2);
    float*          b1e    = (float*)alloc((size_t)NHIDP * 4);
    float*          p      = (float*)alloc((size_t)RES0 * 128 * 4);

    hipMemsetAsync(d_ws, 0, zero_bytes, stream);

    prep_kernel<<<(256 * NHIDP + 128 * NHIDP + NHIDP + 255) / 256, 256, 0, stream>>>(
        W1r, W1n, b1, W2r, W2n, WcatT, W2catT, b1e);

    copyx_kernel<<<(NSRC * NF) / (256 * 8), 256, 0, stream>>>(x, xbf);

    hist_kernel<<<(E0N + 255) / 256, 256, 0, stream>>>(et0, E0N, cnt1);
    hist_kernel<<<(E1N + 255) / 256, 256, 0, stream>>>(et1, E1N, cnt2);
    scan_kernel<<<1, 1024, 0, stream>>>(cnt1, off1, cur1, RES0);
    scan_kernel<<<1, 1024, 0, stream>>>(cnt2, off2, cur2, RES1);
    scatter_kernel<<<(E0N + 255) / 256, 256, 0, stream>>>(es0, et0, E0N, cur1, csr1);
    scatter_kernel<<<(E1N + 255) / 256, 256, 0, stream>>>(es1, et1, E1N, cur2, csr2);

    agg1_csr_kernel<<<RES0, 128, 0, stream>>>(xbf, csr1, off1, cnt1, mean1);

    fused_gemm_kernel<<<(RES0 + 127) / 128, 256, 0, stream>>>(
        xbf, mean1, WcatT, b1e, W2catT, p);

    final_csr_kernel<<<RES1, 64, 0, stream>>>(p, csr2, off2, cnt2, b2, out);
}

// Round 4
// 674.021 us; speedup vs baseline: 1.8773x; 1.1745x over previous
//
#include <hip/hip_runtime.h>
#include <hip/hip_bf16.h>
#include <cstdint>
#include <cstddef>

// Problem constants (from reference)
#define NSRC   200000
#define NF     128
#define NHID   1500
#define NHIDP  1536     // padded hidden dim (multiple of 128)
#define NCLS   64
#define E0N    1600000
#define E1N    500000
#define RES0   50000
#define RES1   10000

// CSR bucket-sort parameters
#define CH     4096                       // edges per chunk
#define NCH0   ((E0N + CH - 1) / CH)      // 391
#define NCH1   ((E1N + CH - 1) / CH)      // 123
#define NB0    ((RES0 + 255) / 256)       // 196 buckets of 256 targets
#define NB1    ((RES1 + 255) / 256)       // 40

typedef __bf16 bf16x8 __attribute__((ext_vector_type(8)));
typedef float  f32x4  __attribute__((ext_vector_type(4)));
typedef unsigned short u16x8 __attribute__((ext_vector_type(8)));
typedef unsigned int u32;
typedef unsigned long long u64;

__device__ __forceinline__ unsigned short f2bf(float f) {
    union { float f; unsigned u; } v; v.f = f;
    unsigned r = v.u + 0x7fffu + ((v.u >> 16) & 1u);   // RNE
    return (unsigned short)(r >> 16);
}
__device__ __forceinline__ float bf2f(unsigned short b) {
    union { unsigned u; float f; } v; v.u = ((unsigned)b) << 16;
    return v.f;
}

// async 16B global -> LDS DMA (dest = wave-uniform lds base + lane*16)
__device__ __forceinline__ void lds_dma16(const void* g, void* lds) {
    __builtin_amdgcn_global_load_lds(
        (const __attribute__((address_space(1))) unsigned int*)g,
        (__attribute__((address_space(3))) unsigned int*)lds, 16, 0, 0);
}

// ---------------- prep: padded/transposed bf16 weights -----------------------
__global__ void prep_kernel(const float* __restrict__ W1r, const float* __restrict__ W1n,
                            const float* __restrict__ b1,
                            const float* __restrict__ W2r, const float* __restrict__ W2n,
                            unsigned short* __restrict__ WcatT,
                            unsigned short* __restrict__ W2catT,
                            float* __restrict__ b1e) {
    int id = blockIdx.x * 256 + threadIdx.x;
    if (id < 256 * NHIDP) {
        int n = id >> 8, k = id & 255;
        float v = 0.f;
        if (n < NHID) v = (k < NF) ? W1r[k * NHID + n] : W1n[(k - NF) * NHID + n];
        WcatT[n * 256 + k] = f2bf(v);
    } else {
        int id2 = id - 256 * NHIDP;
        if (id2 < 128 * NHIDP) {
            int n = id2 / NHIDP, k = id2 % NHIDP;
            float v = 0.f;
            if (k < NHID) v = (n < 64) ? W2n[k * 64 + n] : W2r[k * 64 + (n - 64)];
            W2catT[n * NHIDP + k] = f2bf(v);
        } else {
            int c = id2 - 128 * NHIDP;
            if (c < NHIDP) b1e[c] = (c < NHID) ? b1[c] : 0.f;
        }
    }
}

// ---------------- x -> bf16 copy ---------------------------------------------
__global__ __launch_bounds__(256) void copyx_kernel(const float* __restrict__ x,
                                                    unsigned short* __restrict__ xbf) {
    size_t i = ((size_t)blockIdx.x * 256 + threadIdx.x) * 8;
    const float4* s = (const float4*)(x + i);
    float4 a = s[0], b = s[1];
    u16x8 o;
    o[0] = f2bf(a.x); o[1] = f2bf(a.y); o[2] = f2bf(a.z); o[3] = f2bf(a.w);
    o[4] = f2bf(b.x); o[5] = f2bf(b.y); o[6] = f2bf(b.z); o[7] = f2bf(b.w);
    *(u16x8*)(xbf + i) = o;
}

// ---------------- per-target histogram + scan (unchanged) --------------------
__global__ void hist_kernel(const int* __restrict__ tgt, int n, u32* __restrict__ cnt) {
    int i = blockIdx.x * 256 + threadIdx.x;
    if (i < n) atomicAdd(&cnt[tgt[i]], 1u);
}

__global__ __launch_bounds__(1024) void scan_kernel(const u32* __restrict__ cnt,
                                                    u32* __restrict__ off, int n) {
    __shared__ u32 part[1024];
    int t = threadIdx.x;
    int chunk = (n + 1023) / 1024;
    int s = t * chunk, e = min(s + chunk, n);
    u32 sum = 0;
    for (int i = s; i < e; ++i) sum += cnt[i];
    part[t] = sum;
    __syncthreads();
    for (int d = 1; d < 1024; d <<= 1) {
        u32 v = part[t];
        u32 add = (t >= d) ? part[t - d] : 0u;
        __syncthreads();
        part[t] = v + add;
        __syncthreads();
    }
    u32 run = (t == 0) ? 0u : part[t - 1];
    for (int i = s; i < e; ++i) {
        off[i] = run;
        run += cnt[i];
    }
}

// ---------------- CSR build phase 1a: per-chunk bucket histogram -------------
__global__ __launch_bounds__(256) void p1a_kernel(const int* __restrict__ tgt, int n,
                                                  int nb, u32* __restrict__ H) {
    __shared__ u32 lhist[256];
    int c = blockIdx.x, tid = threadIdx.x;
    lhist[tid] = 0;
    __syncthreads();
#pragma unroll
    for (int it = 0; it < CH / 256; ++it) {
        int i = c * CH + it * 256 + tid;
        if (i < n) atomicAdd(&lhist[((u32)tgt[i]) >> 8], 1u);
    }
    __syncthreads();
    if (tid < nb) H[c * nb + tid] = lhist[tid];
}

// ---------------- phase bscan: per-bucket exclusive scan over chunks ---------
// base[c][b] = off[b<<8] + sum_{c'<c} H[c'][b]
__global__ __launch_bounds__(512) void bscan_kernel(const u32* __restrict__ H,
                                                    const u32* __restrict__ off,
                                                    int nch, int nb, int res,
                                                    u32* __restrict__ base) {
    __shared__ u32 part[512];
    int b = blockIdx.x, t = threadIdx.x;
    part[t] = (t < nch) ? H[t * nb + b] : 0u;
    __syncthreads();
    for (int d = 1; d < 512; d <<= 1) {
        u32 v = part[t];
        u32 add = (t >= d) ? part[t - d] : 0u;
        __syncthreads();
        part[t] = v + add;
        __syncthreads();
    }
    if (t < nch) {
        u32 excl = (t == 0) ? 0u : part[t - 1];
        base[t * nb + b] = off[b << 8] + excl;
    }
}

// ---------------- phase 1b: bucket-grouped scatter of (tgt,src) pairs --------
__global__ __launch_bounds__(256) void p1b_kernel(const int* __restrict__ src,
                                                  const int* __restrict__ tgt, int n,
                                                  int nb, const u32* __restrict__ base,
                                                  u64* __restrict__ bucketed) {
    __shared__ u32 lcur[256];
    __shared__ u32 lbase[256];
    int c = blockIdx.x, tid = threadIdx.x;
    lcur[tid] = 0;
    if (tid < nb) lbase[tid] = base[c * nb + tid];
    __syncthreads();
#pragma unroll
    for (int it = 0; it < CH / 256; ++it) {
        int i = c * CH + it * 256 + tid;
        if (i < n) {
            u32 t = (u32)tgt[i];
            u32 s = (u32)src[i];
            u32 b = t >> 8;
            u32 r = atomicAdd(&lcur[b], 1u);
            bucketed[lbase[b] + r] = ((u64)t << 32) | (u64)s;
        }
    }
}

// ---------------- phase 2: per-bucket local counting sort -> final CSR -------
__global__ __launch_bounds__(1024) void p2_kernel(const u64* __restrict__ bucketed,
                                                  const u32* __restrict__ off,
                                                  int nb, int res, int etot,
                                                  int* __restrict__ csr) {
    __shared__ u32 lhist[256];
    __shared__ u32 part[256];
    __shared__ u32 cur[256];
    int b = blockIdx.x, tid = threadIdx.x;
    u32 start = off[b << 8];
    u32 end = (b == nb - 1) ? (u32)etot : off[(b + 1) << 8];
    u32 count = end - start;
    if (tid < 256) lhist[tid] = 0;
    __syncthreads();
    for (u32 i = tid; i < count; i += 1024) {
        u32 t = (u32)(bucketed[start + i] >> 32);
        atomicAdd(&lhist[t & 255u], 1u);
    }
    __syncthreads();
    if (tid < 256) part[tid] = lhist[tid];
    __syncthreads();
    for (int d = 1; d < 256; d <<= 1) {
        u32 v = (tid < 256) ? part[tid] : 0u;
        u32 add = (tid >= d && tid < 256) ? part[tid - d] : 0u;
        __syncthreads();
        if (tid < 256) part[tid] = v + add;
        __syncthreads();
    }
    if (tid < 256) cur[tid] = (tid == 0) ? 0u : part[tid - 1];
    __syncthreads();
    for (u32 i = tid; i < count; i += 1024) {
        u64 pr = bucketed[start + i];
        u32 lt = ((u32)(pr >> 32)) & 255u;
        u32 r = atomicAdd(&cur[lt], 1u);
        csr[start + r] = (int)(u32)pr;
    }
}

// ---------------- layer-1 mean aggregation (bf16 gathers) --------------------
__global__ __launch_bounds__(128) void agg1_csr_kernel(
        const unsigned short* __restrict__ xbf, const int* __restrict__ csr,
        const u32* __restrict__ off, const u32* __restrict__ cnt,
        unsigned short* __restrict__ mean1) {
    int row = blockIdx.x;
    int c = threadIdx.x;
    u32 base = off[row], deg = cnt[row];
    float a0 = 0.f, a1 = 0.f, a2 = 0.f, a3 = 0.f;
    u32 e = 0;
    for (; e + 4 <= deg; e += 4) {
        int s0 = csr[base + e], s1 = csr[base + e + 1];
        int s2 = csr[base + e + 2], s3 = csr[base + e + 3];
        a0 += bf2f(xbf[(size_t)s0 * NF + c]);
        a1 += bf2f(xbf[(size_t)s1 * NF + c]);
        a2 += bf2f(xbf[(size_t)s2 * NF + c]);
        a3 += bf2f(xbf[(size_t)s3 * NF + c]);
    }
    for (; e < deg; ++e) a0 += bf2f(xbf[(size_t)csr[base + e] * NF + c]);
    float m = ((a0 + a1) + (a2 + a3)) / fmaxf((float)deg, 1.0f);
    mean1[(size_t)row * NF + c] = f2bf(m);
}

// ---------------- fused GEMM: p = relu([xbf|mean1]@Wcat + b1) @ W2cat --------
__global__ __launch_bounds__(256, 2) void fused_gemm_kernel(
        const unsigned short* __restrict__ xbf, const unsigned short* __restrict__ mean1,
        const unsigned short* __restrict__ WcatT, const float* __restrict__ b1e,
        const unsigned short* __restrict__ W2catT, float* __restrict__ p) {
    __shared__ __align__(16) unsigned short As[128 * 32];
    __shared__ __align__(16) unsigned short Bs[128 * 32];
    __shared__ __align__(16) unsigned short Ht[128 * 136];

    int m0 = blockIdx.x * 128;
    int tid = threadIdx.x;
    int lane = tid & 63, wid = tid >> 6;
    int wm = wid >> 1, wn = wid & 1;
    int quad = lane >> 4, l15 = lane & 15;

    f32x4 pacc[4][4] = {};

    for (int j = 0; j < 12; ++j) {
        f32x4 hacc[4][4] = {};
        for (int kk = 0; kk < 256; kk += 32) {
#pragma unroll
            for (int ci = 0; ci < 2; ++ci) {
                int cb = ci * 256 + wid * 64;
                int chunk = cb + lane;
                int n = chunk >> 2, kc = chunk & 3;
                const unsigned short* g = (kk < 128)
                    ? xbf + (size_t)(m0 + n) * NF + kk + kc * 8
                    : mean1 + (size_t)(m0 + n) * NF + (kk - 128) + kc * 8;
                lds_dma16(g, &As[cb * 8]);
            }
#pragma unroll
            for (int ci = 0; ci < 2; ++ci) {
                int cb = ci * 256 + wid * 64;
                int chunk = cb + lane;
                int n = chunk >> 2, kc = chunk & 3;
                const unsigned short* g = WcatT + (size_t)(j * 128 + n) * 256 + kk + kc * 8;
                lds_dma16(g, &Bs[cb * 8]);
            }
            __syncthreads();
            bf16x8 a[4], b[4];
#pragma unroll
            for (int mi = 0; mi < 4; ++mi)
                a[mi] = *(const bf16x8*)(&As[(wm * 64 + mi * 16 + l15) * 32 + quad * 8]);
#pragma unroll
            for (int ni = 0; ni < 4; ++ni)
                b[ni] = *(const bf16x8*)(&Bs[(wn * 64 + ni * 16 + l15) * 32 + quad * 8]);
#pragma unroll
            for (int mi = 0; mi < 4; ++mi)
#pragma unroll
                for (int ni = 0; ni < 4; ++ni)
                    hacc[mi][ni] = __builtin_amdgcn_mfma_f32_16x16x32_bf16(a[mi], b[ni], hacc[mi][ni], 0, 0, 0);
            __syncthreads();
        }
#pragma unroll
        for (int ni = 0; ni < 4; ++ni) {
            int lc = wn * 64 + ni * 16 + l15;
            float bv = b1e[j * 128 + lc];
#pragma unroll
            for (int mi = 0; mi < 4; ++mi) {
#pragma unroll
                for (int r = 0; r < 4; ++r) {
                    int row = wm * 64 + mi * 16 + quad * 4 + r;
                    Ht[row * 136 + lc] = f2bf(fmaxf(hacc[mi][ni][r] + bv, 0.f));
                }
            }
        }
        __syncthreads();
#pragma unroll
        for (int kk2 = 0; kk2 < 128; kk2 += 32) {
            bf16x8 a2[4], b2[4];
#pragma unroll
            for (int mi = 0; mi < 4; ++mi)
                a2[mi] = *(const bf16x8*)(&Ht[(wm * 64 + mi * 16 + l15) * 136 + kk2 + quad * 8]);
#pragma unroll
            for (int ni = 0; ni < 4; ++ni)
                b2[ni] = *(const bf16x8*)(W2catT + (size_t)(wn * 64 + ni * 16 + l15) * NHIDP
                                          + j * 128 + kk2 + quad * 8);
#pragma unroll
            for (int mi = 0; mi < 4; ++mi)
#pragma unroll
                for (int ni = 0; ni < 4; ++ni)
                    pacc[mi][ni] = __builtin_amdgcn_mfma_f32_16x16x32_bf16(a2[mi], b2[ni], pacc[mi][ni], 0, 0, 0);
        }
        __syncthreads();
    }

#pragma unroll
    for (int ni = 0; ni < 4; ++ni) {
        int gc = wn * 64 + ni * 16 + l15;
#pragma unroll
        for (int mi = 0; mi < 4; ++mi) {
#pragma unroll
            for (int r = 0; r < 4; ++r) {
                int gr = m0 + wm * 64 + mi * 16 + quad * 4 + r;
                if (gr < RES0) p[(size_t)gr * 128 + gc] = pacc[mi][ni][r];
            }
        }
    }
}

// ---------------- fused layer-2 aggregation + log_softmax --------------------
__global__ __launch_bounds__(64) void final_csr_kernel(
        const float* __restrict__ p, const int* __restrict__ csr,
        const u32* __restrict__ off, const u32* __restrict__ cnt,
        const float* __restrict__ b2, float* __restrict__ out) {
    int row = blockIdx.x;
    int c = threadIdx.x;
    u32 base = off[row], deg = cnt[row];
    float a0 = 0.f, a1 = 0.f, a2 = 0.f, a3 = 0.f;
    u32 e = 0;
    for (; e + 4 <= deg; e += 4) {
        int s0 = csr[base + e], s1 = csr[base + e + 1];
        int s2 = csr[base + e + 2], s3 = csr[base + e + 3];
        a0 += p[(size_t)s0 * 128 + c];
        a1 += p[(size_t)s1 * 128 + c];
        a2 += p[(size_t)s2 * 128 + c];
        a3 += p[(size_t)s3 * 128 + c];
    }
    for (; e < deg; ++e) a0 += p[(size_t)csr[base + e] * 128 + c];
    float mean = ((a0 + a1) + (a2 + a3)) / fmaxf((float)deg, 1.0f);
    float v = p[(size_t)row * 128 + 64 + c] + mean + b2[c];
    float m = v;
#pragma unroll
    for (int o = 32; o > 0; o >>= 1) m = fmaxf(m, __shfl_xor(m, o, 64));
    float ex = expf(v - m);
    float s = ex;
#pragma unroll
    for (int o = 32; o > 0; o >>= 1) s += __shfl_xor(s, o, 64);
    out[(size_t)row * 64 + c] = v - m - logf(s);
}

extern "C" void kernel_launch(void* const* d_in, const int* in_sizes, int n_in,
                              void* d_out, int out_size, void* d_ws, size_t ws_size,
                              hipStream_t stream) {
    const float* x   = (const float*)d_in[0];
    const float* W1r = (const float*)d_in[1];
    const float* W1n = (const float*)d_in[2];
    const float* b1  = (const float*)d_in[3];
    const float* W2r = (const float*)d_in[4];
    const float* W2n = (const float*)d_in[5];
    const float* b2  = (const float*)d_in[6];
    const int* es0 = (const int*)d_in[7];
    const int* et0 = (const int*)d_in[8];
    const int* es1 = (const int*)d_in[9];
    const int* et1 = (const int*)d_in[10];
    float* out = (float*)d_out;

    char* ws = (char*)d_ws;
    size_t off = 0;
    auto alloc = [&](size_t bytes) {
        void* ptr = ws + off;
        off = (off + bytes + 255) & ~(size_t)255;
        return ptr;
    };
    u32* cnt1 = (u32*)alloc((size_t)RES0 * 4);
    u32* cnt2 = (u32*)alloc((size_t)RES1 * 4);
    size_t zero_bytes = off;
    u32* off1 = (u32*)alloc((size_t)RES0 * 4);
    u32* off2 = (u32*)alloc((size_t)RES1 * 4);
    u32* H1    = (u32*)alloc((size_t)NCH0 * NB0 * 4);
    u32* base1 = (u32*)alloc((size_t)NCH0 * NB0 * 4);
    u32* H2    = (u32*)alloc((size_t)NCH1 * NB1 * 4);
    u32* base2 = (u32*)alloc((size_t)NCH1 * NB1 * 4);
    u64* bkt1  = (u64*)alloc((size_t)E0N * 8);
    u64* bkt2  = (u64*)alloc((size_t)E1N * 8);
    int* csr1 = (int*)alloc((size_t)E0N * 4);
    int* csr2 = (int*)alloc((size_t)E1N * 4);
    unsigned short* xbf    = (unsigned short*)alloc((size_t)NSRC * NF * 2);
    unsigned short* mean1  = (unsigned short*)alloc((size_t)(RES0 + 128) * NF * 2);
    unsigned short* WcatT  = (unsigned short*)alloc((size_t)NHIDP * 256 * 2);
    unsigned short* W2catT = (unsigned short*)alloc((size_t)128 * NHIDP * 2);
    float*          b1e    = (float*)alloc((size_t)NHIDP * 4);
    float*          p      = (float*)alloc((size_t)RES0 * 128 * 4);

    hipMemsetAsync(d_ws, 0, zero_bytes, stream);

    prep_kernel<<<(256 * NHIDP + 128 * NHIDP + NHIDP + 255) / 256, 256, 0, stream>>>(
        W1r, W1n, b1, W2r, W2n, WcatT, W2catT, b1e);

    copyx_kernel<<<(NSRC * NF) / (256 * 8), 256, 0, stream>>>(x, xbf);

    // per-target degree + offsets
    hist_kernel<<<(E0N + 255) / 256, 256, 0, stream>>>(et0, E0N, cnt1);
    hist_kernel<<<(E1N + 255) / 256, 256, 0, stream>>>(et1, E1N, cnt2);
    scan_kernel<<<1, 1024, 0, stream>>>(cnt1, off1, RES0);
    scan_kernel<<<1, 1024, 0, stream>>>(cnt2, off2, RES1);

    // bucket counting sort -> CSR (graph 0)
    p1a_kernel<<<NCH0, 256, 0, stream>>>(et0, E0N, NB0, H1);
    bscan_kernel<<<NB0, 512, 0, stream>>>(H1, off1, NCH0, NB0, RES0, base1);
    p1b_kernel<<<NCH0, 256, 0, stream>>>(es0, et0, E0N, NB0, base1, bkt1);
    p2_kernel<<<NB0, 1024, 0, stream>>>(bkt1, off1, NB0, RES0, E0N, csr1);
    // graph 1
    p1a_kernel<<<NCH1, 256, 0, stream>>>(et1, E1N, NB1, H2);
    bscan_kernel<<<NB1, 512, 0, stream>>>(H2, off2, NCH1, NB1, RES1, base2);
    p1b_kernel<<<NCH1, 256, 0, stream>>>(es1, et1, E1N, NB1, base2, bkt2);
    p2_kernel<<<NB1, 1024, 0, stream>>>(bkt2, off2, NB1, RES1, E1N, csr2);

    agg1_csr_kernel<<<RES0, 128, 0, stream>>>(xbf, csr1, off1, cnt1, mean1);

    fused_gemm_kernel<<<(RES0 + 127) / 128, 256, 0, stream>>>(
        xbf, mean1, WcatT, b1e, W2catT, p);

    final_csr_kernel<<<RES1, 64, 0, stream>>>(p, csr2, off2, cnt2, b2, out);
}

// Round 5
// 590.659 us; speedup vs baseline: 2.1422x; 1.1411x over previous
//
#include <hip/hip_runtime.h>
#include <hip/hip_bf16.h>
#include <cstdint>
#include <cstddef>

// Problem constants (from reference)
#define NSRC   200000
#define NF     128
#define NHID   1500
#define NHIDP  1536     // padded hidden dim (multiple of 128)
#define NCLS   64
#define E0N    1600000
#define E1N    500000
#define RES0   50000
#define RES1   10000

// CSR bucket-sort parameters
#define CH     4096                       // edges per chunk
#define NCH0   ((E0N + CH - 1) / CH)      // 391
#define NCH1   ((E1N + CH - 1) / CH)      // 123
#define NB0    ((RES0 + 255) / 256)       // 196 buckets of 256 targets
#define NB1    ((RES1 + 255) / 256)       // 40

typedef __bf16 bf16x8 __attribute__((ext_vector_type(8)));
typedef float  f32x4  __attribute__((ext_vector_type(4)));
typedef unsigned short u16x8 __attribute__((ext_vector_type(8)));
typedef unsigned int u32;
typedef unsigned long long u64;

__device__ __forceinline__ unsigned short f2bf(float f) {
    union { float f; unsigned u; } v; v.f = f;
    unsigned r = v.u + 0x7fffu + ((v.u >> 16) & 1u);   // RNE
    return (unsigned short)(r >> 16);
}

// async 16B global -> LDS DMA (dest = wave-uniform lds base + lane*16)
__device__ __forceinline__ void lds_dma16(const void* g, void* lds) {
    __builtin_amdgcn_global_load_lds(
        (const __attribute__((address_space(1))) unsigned int*)g,
        (__attribute__((address_space(3))) unsigned int*)lds, 16, 0, 0);
}

// ---------------- prep: padded/transposed bf16 weights -----------------------
__global__ void prep_kernel(const float* __restrict__ W1r, const float* __restrict__ W1n,
                            const float* __restrict__ b1,
                            const float* __restrict__ W2r, const float* __restrict__ W2n,
                            unsigned short* __restrict__ WcatT,
                            unsigned short* __restrict__ W2catT,
                            float* __restrict__ b1e) {
    int id = blockIdx.x * 256 + threadIdx.x;
    if (id < 256 * NHIDP) {
        int n = id >> 8, k = id & 255;
        float v = 0.f;
        if (n < NHID) v = (k < NF) ? W1r[k * NHID + n] : W1n[(k - NF) * NHID + n];
        WcatT[n * 256 + k] = f2bf(v);
    } else {
        int id2 = id - 256 * NHIDP;
        if (id2 < 128 * NHIDP) {
            int n = id2 / NHIDP, k = id2 % NHIDP;
            float v = 0.f;
            if (k < NHID) v = (n < 64) ? W2n[k * 64 + n] : W2r[k * 64 + (n - 64)];
            W2catT[n * NHIDP + k] = f2bf(v);
        } else {
            int c = id2 - 128 * NHIDP;
            if (c < NHIDP) b1e[c] = (c < NHID) ? b1[c] : 0.f;
        }
    }
}

// ---------------- x -> bf16 copy ---------------------------------------------
__global__ __launch_bounds__(256) void copyx_kernel(const float* __restrict__ x,
                                                    unsigned short* __restrict__ xbf) {
    size_t i = ((size_t)blockIdx.x * 256 + threadIdx.x) * 8;
    const float4* s = (const float4*)(x + i);
    float4 a = s[0], b = s[1];
    u16x8 o;
    o[0] = f2bf(a.x); o[1] = f2bf(a.y); o[2] = f2bf(a.z); o[3] = f2bf(a.w);
    o[4] = f2bf(b.x); o[5] = f2bf(b.y); o[6] = f2bf(b.z); o[7] = f2bf(b.w);
    *(u16x8*)(xbf + i) = o;
}

// ---------------- CSR phase 1a: per-chunk bucket histogram -------------------
__global__ __launch_bounds__(256) void p1a_kernel(const int* __restrict__ tgt, int n,
                                                  int nb, u32* __restrict__ H) {
    __shared__ u32 lhist[256];
    int c = blockIdx.x, tid = threadIdx.x;
    lhist[tid] = 0;
    __syncthreads();
#pragma unroll
    for (int it = 0; it < CH / 256; ++it) {
        int i = c * CH + it * 256 + tid;
        if (i < n) atomicAdd(&lhist[((u32)tgt[i]) >> 8], 1u);
    }
    __syncthreads();
    if (tid < nb) H[c * nb + tid] = lhist[tid];
}

// ---------------- bscan: per-bucket exclusive scan over chunks + totals ------
__global__ __launch_bounds__(512) void bscan_kernel(const u32* __restrict__ H,
                                                    int nch, int nb,
                                                    u32* __restrict__ base_rel,
                                                    u32* __restrict__ Bsum) {
    __shared__ u32 part[512];
    int b = blockIdx.x, t = threadIdx.x;
    part[t] = (t < nch) ? H[t * nb + b] : 0u;
    __syncthreads();
    for (int d = 1; d < 512; d <<= 1) {
        u32 v = part[t];
        u32 add = (t >= d) ? part[t - d] : 0u;
        __syncthreads();
        part[t] = v + add;
        __syncthreads();
    }
    if (t < nch) base_rel[t * nb + b] = (t == 0) ? 0u : part[t - 1];
    if (t == 0) Bsum[b] = part[nch - 1];
}

// ---------------- boff: exclusive scan over bucket totals (both graphs) ------
__global__ __launch_bounds__(256) void boff_kernel(const u32* __restrict__ Bsum1,
                                                   u32* __restrict__ boff1, int nb1,
                                                   const u32* __restrict__ Bsum2,
                                                   u32* __restrict__ boff2, int nb2) {
    const u32* B = blockIdx.x ? Bsum2 : Bsum1;
    u32* O = blockIdx.x ? boff2 : boff1;
    int nb = blockIdx.x ? nb2 : nb1;
    __shared__ u32 part[256];
    int t = threadIdx.x;
    part[t] = (t < nb) ? B[t] : 0u;
    __syncthreads();
    for (int d = 1; d < 256; d <<= 1) {
        u32 v = part[t];
        u32 add = (t >= d) ? part[t - d] : 0u;
        __syncthreads();
        part[t] = v + add;
        __syncthreads();
    }
    if (t < nb) O[t] = (t == 0) ? 0u : part[t - 1];
}

// ---------------- phase 1b: bucket-grouped scatter of (tgt,src) pairs --------
__global__ __launch_bounds__(256) void p1b_kernel(const int* __restrict__ src,
                                                  const int* __restrict__ tgt, int n,
                                                  int nb, const u32* __restrict__ base_rel,
                                                  const u32* __restrict__ boff,
                                                  u64* __restrict__ bucketed) {
    __shared__ u32 lcur[256];
    __shared__ u32 lbase[256];
    int c = blockIdx.x, tid = threadIdx.x;
    lcur[tid] = 0;
    if (tid < nb) lbase[tid] = base_rel[c * nb + tid] + boff[tid];
    __syncthreads();
#pragma unroll
    for (int it = 0; it < CH / 256; ++it) {
        int i = c * CH + it * 256 + tid;
        if (i < n) {
            u32 t = (u32)tgt[i];
            u32 s = (u32)src[i];
            u32 b = t >> 8;
            u32 r = atomicAdd(&lcur[b], 1u);
            bucketed[lbase[b] + r] = ((u64)t << 32) | (u64)s;
        }
    }
}

// ---------------- phase 2: per-bucket sort -> CSR + per-target off/cnt -------
__global__ __launch_bounds__(1024) void p2_kernel(const u64* __restrict__ bucketed,
                                                  const u32* __restrict__ boff,
                                                  int nb, int res, int etot,
                                                  int* __restrict__ csr,
                                                  u32* __restrict__ off_out,
                                                  u32* __restrict__ cnt_out) {
    __shared__ u32 lhist[256];
    __shared__ u32 part[256];
    __shared__ u32 cur[256];
    int b = blockIdx.x, tid = threadIdx.x;
    u32 start = boff[b];
    u32 end = (b == nb - 1) ? (u32)etot : boff[b + 1];
    u32 count = end - start;
    if (tid < 256) lhist[tid] = 0;
    __syncthreads();
    for (u32 i = tid; i < count; i += 1024) {
        u32 t = (u32)(bucketed[start + i] >> 32);
        atomicAdd(&lhist[t & 255u], 1u);
    }
    __syncthreads();
    if (tid < 256) part[tid] = lhist[tid];
    __syncthreads();
    for (int d = 1; d < 256; d <<= 1) {
        u32 v = (tid < 256) ? part[tid] : 0u;
        u32 add = (tid >= d && tid < 256) ? part[tid - d] : 0u;
        __syncthreads();
        if (tid < 256) part[tid] = v + add;
        __syncthreads();
    }
    if (tid < 256) {
        u32 excl = (tid == 0) ? 0u : part[tid - 1];
        cur[tid] = excl;
        int tg = (b << 8) + tid;
        if (tg < res) {
            off_out[tg] = start + excl;
            cnt_out[tg] = lhist[tid];
        }
    }
    __syncthreads();
    for (u32 i = tid; i < count; i += 1024) {
        u64 pr = bucketed[start + i];
        u32 lt = ((u32)(pr >> 32)) & 255u;
        u32 r = atomicAdd(&cur[lt], 1u);
        csr[start + r] = (int)(u32)pr;
    }
}

// ---------------- layer-1 mean aggregation: 1 wave/row, u32 gathers ----------
__global__ __launch_bounds__(256) void agg1_csr_kernel(
        const u32* __restrict__ xb32, const int* __restrict__ csr,
        const u32* __restrict__ off, const u32* __restrict__ cnt,
        u32* __restrict__ mean1_32) {
    int row = blockIdx.x * 4 + (threadIdx.x >> 6);
    int lane = threadIdx.x & 63;
    if (row >= RES0) return;
    u32 base = off[row], deg = cnt[row];
    float x0 = 0.f, y0 = 0.f, x1 = 0.f, y1 = 0.f;
    float x2 = 0.f, y2 = 0.f, x3 = 0.f, y3 = 0.f;
    u32 e = 0;
    for (; e + 4 <= deg; e += 4) {
        int s0 = csr[base + e], s1 = csr[base + e + 1];
        int s2 = csr[base + e + 2], s3 = csr[base + e + 3];
        u32 w0 = xb32[(size_t)s0 * 64 + lane];
        u32 w1 = xb32[(size_t)s1 * 64 + lane];
        u32 w2 = xb32[(size_t)s2 * 64 + lane];
        u32 w3 = xb32[(size_t)s3 * 64 + lane];
        union { u32 u; float f; } a, b;
        a.u = w0 << 16; b.u = w0 & 0xffff0000u; x0 += a.f; y0 += b.f;
        a.u = w1 << 16; b.u = w1 & 0xffff0000u; x1 += a.f; y1 += b.f;
        a.u = w2 << 16; b.u = w2 & 0xffff0000u; x2 += a.f; y2 += b.f;
        a.u = w3 << 16; b.u = w3 & 0xffff0000u; x3 += a.f; y3 += b.f;
    }
    for (; e < deg; ++e) {
        u32 w = xb32[(size_t)csr[base + e] * 64 + lane];
        union { u32 u; float f; } a, b;
        a.u = w << 16; b.u = w & 0xffff0000u; x0 += a.f; y0 += b.f;
    }
    float inv = 1.0f / fmaxf((float)deg, 1.0f);
    float mx = ((x0 + x1) + (x2 + x3)) * inv;
    float my = ((y0 + y1) + (y2 + y3)) * inv;
    mean1_32[(size_t)row * 64 + lane] = (u32)f2bf(mx) | ((u32)f2bf(my) << 16);
}

// ---------------- fused GEMM: partial-p over 6 j-chunks per block ------------
// grid (391, 2): y selects j-range [0,6) / [6,12) and the output partial buffer
__global__ __launch_bounds__(256, 3) void fused_gemm_kernel(
        const unsigned short* __restrict__ xbf, const unsigned short* __restrict__ mean1,
        const unsigned short* __restrict__ WcatT, const float* __restrict__ b1e,
        const unsigned short* __restrict__ W2catT,
        float* __restrict__ pp0, float* __restrict__ pp1) {
    __shared__ __align__(16) unsigned short As[128 * 32];
    __shared__ __align__(16) unsigned short Bs[128 * 32];
    __shared__ __align__(16) unsigned short Ht[128 * 136];

    int m0 = blockIdx.x * 128;
    int jb = blockIdx.y * 6;
    float* pout = blockIdx.y ? pp1 : pp0;
    int tid = threadIdx.x;
    int lane = tid & 63, wid = tid >> 6;
    int wm = wid >> 1, wn = wid & 1;
    int quad = lane >> 4, l15 = lane & 15;

    f32x4 pacc[4][4] = {};

    for (int j = jb; j < jb + 6; ++j) {
        f32x4 hacc[4][4] = {};
        for (int kk = 0; kk < 256; kk += 32) {
#pragma unroll
            for (int ci = 0; ci < 2; ++ci) {
                int cb = ci * 256 + wid * 64;
                int chunk = cb + lane;
                int n = chunk >> 2, kc = chunk & 3;
                const unsigned short* g = (kk < 128)
                    ? xbf + (size_t)(m0 + n) * NF + kk + kc * 8
                    : mean1 + (size_t)(m0 + n) * NF + (kk - 128) + kc * 8;
                lds_dma16(g, &As[cb * 8]);
            }
#pragma unroll
            for (int ci = 0; ci < 2; ++ci) {
                int cb = ci * 256 + wid * 64;
                int chunk = cb + lane;
                int n = chunk >> 2, kc = chunk & 3;
                const unsigned short* g = WcatT + (size_t)(j * 128 + n) * 256 + kk + kc * 8;
                lds_dma16(g, &Bs[cb * 8]);
            }
            __syncthreads();
            bf16x8 a[4], b[4];
#pragma unroll
            for (int mi = 0; mi < 4; ++mi)
                a[mi] = *(const bf16x8*)(&As[(wm * 64 + mi * 16 + l15) * 32 + quad * 8]);
#pragma unroll
            for (int ni = 0; ni < 4; ++ni)
                b[ni] = *(const bf16x8*)(&Bs[(wn * 64 + ni * 16 + l15) * 32 + quad * 8]);
#pragma unroll
            for (int mi = 0; mi < 4; ++mi)
#pragma unroll
                for (int ni = 0; ni < 4; ++ni)
                    hacc[mi][ni] = __builtin_amdgcn_mfma_f32_16x16x32_bf16(a[mi], b[ni], hacc[mi][ni], 0, 0, 0);
            __syncthreads();
        }
#pragma unroll
        for (int ni = 0; ni < 4; ++ni) {
            int lc = wn * 64 + ni * 16 + l15;
            float bv = b1e[j * 128 + lc];
#pragma unroll
            for (int mi = 0; mi < 4; ++mi) {
#pragma unroll
                for (int r = 0; r < 4; ++r) {
                    int row = wm * 64 + mi * 16 + quad * 4 + r;
                    Ht[row * 136 + lc] = f2bf(fmaxf(hacc[mi][ni][r] + bv, 0.f));
                }
            }
        }
        __syncthreads();
#pragma unroll
        for (int kk2 = 0; kk2 < 128; kk2 += 32) {
            bf16x8 a2[4], b2[4];
#pragma unroll
            for (int mi = 0; mi < 4; ++mi)
                a2[mi] = *(const bf16x8*)(&Ht[(wm * 64 + mi * 16 + l15) * 136 + kk2 + quad * 8]);
#pragma unroll
            for (int ni = 0; ni < 4; ++ni)
                b2[ni] = *(const bf16x8*)(W2catT + (size_t)(wn * 64 + ni * 16 + l15) * NHIDP
                                          + j * 128 + kk2 + quad * 8);
#pragma unroll
            for (int mi = 0; mi < 4; ++mi)
#pragma unroll
                for (int ni = 0; ni < 4; ++ni)
                    pacc[mi][ni] = __builtin_amdgcn_mfma_f32_16x16x32_bf16(a2[mi], b2[ni], pacc[mi][ni], 0, 0, 0);
        }
        __syncthreads();
    }

#pragma unroll
    for (int ni = 0; ni < 4; ++ni) {
        int gc = wn * 64 + ni * 16 + l15;
#pragma unroll
        for (int mi = 0; mi < 4; ++mi) {
#pragma unroll
            for (int r = 0; r < 4; ++r) {
                int gr = m0 + wm * 64 + mi * 16 + quad * 4 + r;
                if (gr < RES0) pout[(size_t)gr * 128 + gc] = pacc[mi][ni][r];
            }
        }
    }
}

// ---------------- padd: pp0 += pp1 ------------------------------------------
__global__ __launch_bounds__(256) void padd_kernel(float* __restrict__ pp0,
                                                   const float* __restrict__ pp1) {
    size_t i = (size_t)blockIdx.x * 256 + threadIdx.x;
    f32x4 a = ((const f32x4*)pp0)[i];
    f32x4 b = ((const f32x4*)pp1)[i];
    ((f32x4*)pp0)[i] = a + b;
}

// ---------------- fused layer-2 aggregation + log_softmax --------------------
__global__ __launch_bounds__(64) void final_csr_kernel(
        const float* __restrict__ p, const int* __restrict__ csr,
        const u32* __restrict__ off, const u32* __restrict__ cnt,
        const float* __restrict__ b2, float* __restrict__ out) {
    int row = blockIdx.x;
    int c = threadIdx.x;
    u32 base = off[row], deg = cnt[row];
    float a0 = 0.f, a1 = 0.f, a2 = 0.f, a3 = 0.f;
    u32 e = 0;
    for (; e + 4 <= deg; e += 4) {
        int s0 = csr[base + e], s1 = csr[base + e + 1];
        int s2 = csr[base + e + 2], s3 = csr[base + e + 3];
        a0 += p[(size_t)s0 * 128 + c];
        a1 += p[(size_t)s1 * 128 + c];
        a2 += p[(size_t)s2 * 128 + c];
        a3 += p[(size_t)s3 * 128 + c];
    }
    for (; e < deg; ++e) a0 += p[(size_t)csr[base + e] * 128 + c];
    float mean = ((a0 + a1) + (a2 + a3)) / fmaxf((float)deg, 1.0f);
    float v = p[(size_t)row * 128 + 64 + c] + mean + b2[c];
    float m = v;
#pragma unroll
    for (int o = 32; o > 0; o >>= 1) m = fmaxf(m, __shfl_xor(m, o, 64));
    float ex = expf(v - m);
    float s = ex;
#pragma unroll
    for (int o = 32; o > 0; o >>= 1) s += __shfl_xor(s, o, 64);
    out[(size_t)row * 64 + c] = v - m - logf(s);
}

extern "C" void kernel_launch(void* const* d_in, const int* in_sizes, int n_in,
                              void* d_out, int out_size, void* d_ws, size_t ws_size,
                              hipStream_t stream) {
    const float* x   = (const float*)d_in[0];
    const float* W1r = (const float*)d_in[1];
    const float* W1n = (const float*)d_in[2];
    const float* b1  = (const float*)d_in[3];
    const float* W2r = (const float*)d_in[4];
    const float* W2n = (const float*)d_in[5];
    const float* b2  = (const float*)d_in[6];
    const int* es0 = (const int*)d_in[7];
    const int* et0 = (const int*)d_in[8];
    const int* es1 = (const int*)d_in[9];
    const int* et1 = (const int*)d_in[10];
    float* out = (float*)d_out;

    char* ws = (char*)d_ws;
    // --- region 0 [0, 25.6 MB): pp1 aliases CSR-phase temporaries (all dead
    //     before fused_gemm writes pp1) ---
    const size_t PPBYTES = (size_t)RES0 * 128 * 4;   // 25,600,000
    float* pp1 = (float*)ws;
    size_t o0 = 0;
    auto alloc0 = [&](size_t bytes) {
        void* ptr = ws + o0;
        o0 = (o0 + bytes + 255) & ~(size_t)255;
        return ptr;
    };
    u64* bkt1  = (u64*)alloc0((size_t)E0N * 8);        // 12.8 MB
    u64* bkt2  = (u64*)alloc0((size_t)E1N * 8);        //  4.0 MB
    int* csr1  = (int*)alloc0((size_t)E0N * 4);        //  6.4 MB
    u32* H1    = (u32*)alloc0((size_t)NCH0 * NB0 * 4);
    u32* base1 = (u32*)alloc0((size_t)NCH0 * NB0 * 4);
    u32* H2    = (u32*)alloc0((size_t)NCH1 * NB1 * 4);
    u32* base2 = (u32*)alloc0((size_t)NCH1 * NB1 * 4);
    u32* Bsum1 = (u32*)alloc0((size_t)NB0 * 4);
    u32* Bsum2 = (u32*)alloc0((size_t)NB1 * 4);
    u32* boff1 = (u32*)alloc0((size_t)NB0 * 4);
    u32* boff2 = (u32*)alloc0((size_t)NB1 * 4);
    u32* off1  = (u32*)alloc0((size_t)RES0 * 4);
    u32* cnt1  = (u32*)alloc0((size_t)RES0 * 4);
    // (o0 ≈ 24.3 MB < 25.6 MB — fits under pp1)

    // --- live region, starts after pp1 ---
    size_t off_ = PPBYTES;                              // 25,600,000 (256-aligned)
    auto alloc = [&](size_t bytes) {
        void* ptr = ws + off_;
        off_ = (off_ + bytes + 255) & ~(size_t)255;
        return ptr;
    };
    int* csr2  = (int*)alloc((size_t)E1N * 4);
    u32* off2  = (u32*)alloc((size_t)RES1 * 4);
    u32* cnt2  = (u32*)alloc((size_t)RES1 * 4);
    unsigned short* xbf    = (unsigned short*)alloc((size_t)NSRC * NF * 2);
    unsigned short* mean1  = (unsigned short*)alloc((size_t)(RES0 + 128) * NF * 2);
    unsigned short* WcatT  = (unsigned short*)alloc((size_t)NHIDP * 256 * 2);
    unsigned short* W2catT = (unsigned short*)alloc((size_t)128 * NHIDP * 2);
    float*          b1e    = (float*)alloc((size_t)NHIDP * 4);
    float*          pp0    = (float*)alloc(PPBYTES);

    prep_kernel<<<(256 * NHIDP + 128 * NHIDP + NHIDP + 255) / 256, 256, 0, stream>>>(
        W1r, W1n, b1, W2r, W2n, WcatT, W2catT, b1e);

    copyx_kernel<<<(NSRC * NF) / (256 * 8), 256, 0, stream>>>(x, xbf);

    // bucket counting sort -> CSR (+ per-target off/cnt from p2)
    p1a_kernel<<<NCH0, 256, 0, stream>>>(et0, E0N, NB0, H1);
    p1a_kernel<<<NCH1, 256, 0, stream>>>(et1, E1N, NB1, H2);
    bscan_kernel<<<NB0, 512, 0, stream>>>(H1, NCH0, NB0, base1, Bsum1);
    bscan_kernel<<<NB1, 512, 0, stream>>>(H2, NCH1, NB1, base2, Bsum2);
    boff_kernel<<<2, 256, 0, stream>>>(Bsum1, boff1, NB0, Bsum2, boff2, NB1);
    p1b_kernel<<<NCH0, 256, 0, stream>>>(es0, et0, E0N, NB0, base1, boff1, bkt1);
    p1b_kernel<<<NCH1, 256, 0, stream>>>(es1, et1, E1N, NB1, base2, boff2, bkt2);
    p2_kernel<<<NB0, 1024, 0, stream>>>(bkt1, boff1, NB0, RES0, E0N, csr1, off1, cnt1);
    p2_kernel<<<NB1, 1024, 0, stream>>>(bkt2, boff2, NB1, RES1, E1N, csr2, off2, cnt2);

    agg1_csr_kernel<<<(RES0 + 3) / 4, 256, 0, stream>>>(
        (const u32*)xbf, csr1, off1, cnt1, (u32*)mean1);

    fused_gemm_kernel<<<dim3((RES0 + 127) / 128, 2), 256, 0, stream>>>(
        xbf, mean1, WcatT, b1e, W2catT, pp0, pp1);

    padd_kernel<<<(RES0 * 128 / 4 + 255) / 256, 256, 0, stream>>>(pp0, pp1);

    final_csr_kernel<<<RES1, 64, 0, stream>>>(pp0, csr2, off2, cnt2, b2, out);
}

// Round 6
// 499.538 us; speedup vs baseline: 2.5330x; 1.1824x over previous
//
#include <hip/hip_runtime.h>
#include <hip/hip_bf16.h>
#include <cstdint>
#include <cstddef>

// Problem constants (from reference)
#define NSRC   200000
#define NF     128
#define NHID   1500
#define NHIDP  1536     // padded hidden dim (multiple of 128)
#define NCLS   64
#define E0N    1600000
#define E1N    500000
#define RES0   50000
#define RES1   10000

// CSR bucket-sort parameters
#define CH     4096                       // edges per chunk
#define NCH0   ((E0N + CH - 1) / CH)      // 391
#define NCH1   ((E1N + CH - 1) / CH)      // 123
#define NB0    ((RES0 + 255) / 256)       // 196 buckets of 256 targets
#define NB1    ((RES1 + 255) / 256)       // 40

typedef __bf16 bf16x8 __attribute__((ext_vector_type(8)));
typedef float  f32x4  __attribute__((ext_vector_type(4)));
typedef unsigned short u16x8 __attribute__((ext_vector_type(8)));
typedef unsigned int u32;
typedef unsigned long long u64;

__device__ __forceinline__ unsigned short f2bf(float f) {
    union { float f; unsigned u; } v; v.f = f;
    unsigned r = v.u + 0x7fffu + ((v.u >> 16) & 1u);   // RNE
    return (unsigned short)(r >> 16);
}

// async 16B global -> LDS DMA (dest = wave-uniform lds base + lane*16)
__device__ __forceinline__ void lds_dma16(const void* g, void* lds) {
    __builtin_amdgcn_global_load_lds(
        (const __attribute__((address_space(1))) unsigned int*)g,
        (__attribute__((address_space(3))) unsigned int*)lds, 16, 0, 0);
}

// ---------------- prep: padded/transposed bf16 weights -----------------------
__global__ void prep_kernel(const float* __restrict__ W1r, const float* __restrict__ W1n,
                            const float* __restrict__ b1,
                            const float* __restrict__ W2r, const float* __restrict__ W2n,
                            unsigned short* __restrict__ WcatT,
                            unsigned short* __restrict__ W2catT,
                            float* __restrict__ b1e) {
    int id = blockIdx.x * 256 + threadIdx.x;
    if (id < 256 * NHIDP) {
        int n = id >> 8, k = id & 255;
        float v = 0.f;
        if (n < NHID) v = (k < NF) ? W1r[k * NHID + n] : W1n[(k - NF) * NHID + n];
        WcatT[n * 256 + k] = f2bf(v);
    } else {
        int id2 = id - 256 * NHIDP;
        if (id2 < 128 * NHIDP) {
            int n = id2 / NHIDP, k = id2 % NHIDP;
            float v = 0.f;
            if (k < NHID) v = (n < 64) ? W2n[k * 64 + n] : W2r[k * 64 + (n - 64)];
            W2catT[n * NHIDP + k] = f2bf(v);
        } else {
            int c = id2 - 128 * NHIDP;
            if (c < NHIDP) b1e[c] = (c < NHID) ? b1[c] : 0.f;
        }
    }
}

// ---------------- x -> bf16 copy ---------------------------------------------
__global__ __launch_bounds__(256) void copyx_kernel(const float* __restrict__ x,
                                                    unsigned short* __restrict__ xbf) {
    size_t i = ((size_t)blockIdx.x * 256 + threadIdx.x) * 8;
    const float4* s = (const float4*)(x + i);
    float4 a = s[0], b = s[1];
    u16x8 o;
    o[0] = f2bf(a.x); o[1] = f2bf(a.y); o[2] = f2bf(a.z); o[3] = f2bf(a.w);
    o[4] = f2bf(b.x); o[5] = f2bf(b.y); o[6] = f2bf(b.z); o[7] = f2bf(b.w);
    *(u16x8*)(xbf + i) = o;
}

// ---------------- CSR phase 1a: per-chunk bucket histogram -------------------
__global__ __launch_bounds__(256) void p1a_kernel(const int* __restrict__ tgt, int n,
                                                  int nb, u32* __restrict__ H) {
    __shared__ u32 lhist[256];
    int c = blockIdx.x, tid = threadIdx.x;
    lhist[tid] = 0;
    __syncthreads();
#pragma unroll
    for (int it = 0; it < CH / 256; ++it) {
        int i = c * CH + it * 256 + tid;
        if (i < n) atomicAdd(&lhist[((u32)tgt[i]) >> 8], 1u);
    }
    __syncthreads();
    if (tid < nb) H[c * nb + tid] = lhist[tid];
}

// ---------------- bscan: per-bucket exclusive scan over chunks + totals ------
__global__ __launch_bounds__(512) void bscan_kernel(const u32* __restrict__ H,
                                                    int nch, int nb,
                                                    u32* __restrict__ base_rel,
                                                    u32* __restrict__ Bsum) {
    __shared__ u32 part[512];
    int b = blockIdx.x, t = threadIdx.x;
    part[t] = (t < nch) ? H[t * nb + b] : 0u;
    __syncthreads();
    for (int d = 1; d < 512; d <<= 1) {
        u32 v = part[t];
        u32 add = (t >= d) ? part[t - d] : 0u;
        __syncthreads();
        part[t] = v + add;
        __syncthreads();
    }
    if (t < nch) base_rel[t * nb + b] = (t == 0) ? 0u : part[t - 1];
    if (t == 0) Bsum[b] = part[nch - 1];
}

// ---------------- boff: exclusive scan over bucket totals (both graphs) ------
__global__ __launch_bounds__(256) void boff_kernel(const u32* __restrict__ Bsum1,
                                                   u32* __restrict__ boff1, int nb1,
                                                   const u32* __restrict__ Bsum2,
                                                   u32* __restrict__ boff2, int nb2) {
    const u32* B = blockIdx.x ? Bsum2 : Bsum1;
    u32* O = blockIdx.x ? boff2 : boff1;
    int nb = blockIdx.x ? nb2 : nb1;
    __shared__ u32 part[256];
    int t = threadIdx.x;
    part[t] = (t < nb) ? B[t] : 0u;
    __syncthreads();
    for (int d = 1; d < 256; d <<= 1) {
        u32 v = part[t];
        u32 add = (t >= d) ? part[t - d] : 0u;
        __syncthreads();
        part[t] = v + add;
        __syncthreads();
    }
    if (t < nb) O[t] = (t == 0) ? 0u : part[t - 1];
}

// ---------------- phase 1b: bucket-grouped scatter of (tgt,src) pairs --------
__global__ __launch_bounds__(256) void p1b_kernel(const int* __restrict__ src,
                                                  const int* __restrict__ tgt, int n,
                                                  int nb, const u32* __restrict__ base_rel,
                                                  const u32* __restrict__ boff,
                                                  u64* __restrict__ bucketed) {
    __shared__ u32 lcur[256];
    __shared__ u32 lbase[256];
    int c = blockIdx.x, tid = threadIdx.x;
    lcur[tid] = 0;
    if (tid < nb) lbase[tid] = base_rel[c * nb + tid] + boff[tid];
    __syncthreads();
#pragma unroll
    for (int it = 0; it < CH / 256; ++it) {
        int i = c * CH + it * 256 + tid;
        if (i < n) {
            u32 t = (u32)tgt[i];
            u32 s = (u32)src[i];
            u32 b = t >> 8;
            u32 r = atomicAdd(&lcur[b], 1u);
            bucketed[lbase[b] + r] = ((u64)t << 32) | (u64)s;
        }
    }
}

// ---------------- phase 2: per-bucket sort -> CSR + per-target off/cnt -------
__global__ __launch_bounds__(1024) void p2_kernel(const u64* __restrict__ bucketed,
                                                  const u32* __restrict__ boff,
                                                  int nb, int res, int etot,
                                                  int* __restrict__ csr,
                                                  u32* __restrict__ off_out,
                                                  u32* __restrict__ cnt_out) {
    __shared__ u32 lhist[256];
    __shared__ u32 part[256];
    __shared__ u32 cur[256];
    int b = blockIdx.x, tid = threadIdx.x;
    u32 start = boff[b];
    u32 end = (b == nb - 1) ? (u32)etot : boff[b + 1];
    u32 count = end - start;
    if (tid < 256) lhist[tid] = 0;
    __syncthreads();
    for (u32 i = tid; i < count; i += 1024) {
        u32 t = (u32)(bucketed[start + i] >> 32);
        atomicAdd(&lhist[t & 255u], 1u);
    }
    __syncthreads();
    if (tid < 256) part[tid] = lhist[tid];
    __syncthreads();
    for (int d = 1; d < 256; d <<= 1) {
        u32 v = (tid < 256) ? part[tid] : 0u;
        u32 add = (tid >= d && tid < 256) ? part[tid - d] : 0u;
        __syncthreads();
        if (tid < 256) part[tid] = v + add;
        __syncthreads();
    }
    if (tid < 256) {
        u32 excl = (tid == 0) ? 0u : part[tid - 1];
        cur[tid] = excl;
        int tg = (b << 8) + tid;
        if (tg < res) {
            off_out[tg] = start + excl;
            cnt_out[tg] = lhist[tid];
        }
    }
    __syncthreads();
    for (u32 i = tid; i < count; i += 1024) {
        u64 pr = bucketed[start + i];
        u32 lt = ((u32)(pr >> 32)) & 255u;
        u32 r = atomicAdd(&cur[lt], 1u);
        csr[start + r] = (int)(u32)pr;
    }
}

// ---------------- layer-1 mean aggregation: 1 wave/row, u32 gathers ----------
__global__ __launch_bounds__(256) void agg1_csr_kernel(
        const u32* __restrict__ xb32, const int* __restrict__ csr,
        const u32* __restrict__ off, const u32* __restrict__ cnt,
        u32* __restrict__ mean1_32) {
    int row = blockIdx.x * 4 + (threadIdx.x >> 6);
    int lane = threadIdx.x & 63;
    if (row >= RES0) return;
    u32 base = off[row], deg = cnt[row];
    float x0 = 0.f, y0 = 0.f, x1 = 0.f, y1 = 0.f;
    float x2 = 0.f, y2 = 0.f, x3 = 0.f, y3 = 0.f;
    u32 e = 0;
    for (; e + 4 <= deg; e += 4) {
        int s0 = csr[base + e], s1 = csr[base + e + 1];
        int s2 = csr[base + e + 2], s3 = csr[base + e + 3];
        u32 w0 = xb32[(size_t)s0 * 64 + lane];
        u32 w1 = xb32[(size_t)s1 * 64 + lane];
        u32 w2 = xb32[(size_t)s2 * 64 + lane];
        u32 w3 = xb32[(size_t)s3 * 64 + lane];
        union { u32 u; float f; } a, b;
        a.u = w0 << 16; b.u = w0 & 0xffff0000u; x0 += a.f; y0 += b.f;
        a.u = w1 << 16; b.u = w1 & 0xffff0000u; x1 += a.f; y1 += b.f;
        a.u = w2 << 16; b.u = w2 & 0xffff0000u; x2 += a.f; y2 += b.f;
        a.u = w3 << 16; b.u = w3 & 0xffff0000u; x3 += a.f; y3 += b.f;
    }
    for (; e < deg; ++e) {
        u32 w = xb32[(size_t)csr[base + e] * 64 + lane];
        union { u32 u; float f; } a, b;
        a.u = w << 16; b.u = w & 0xffff0000u; x0 += a.f; y0 += b.f;
    }
    float inv = 1.0f / fmaxf((float)deg, 1.0f);
    float mx = ((x0 + x1) + (x2 + x3)) * inv;
    float my = ((y0 + y1) + (y2 + y3)) * inv;
    mean1_32[(size_t)row * 64 + lane] = (u32)f2bf(mx) | ((u32)f2bf(my) << 16);
}

// ---------------- fused GEMM: partial-p over 6 j-chunks per block ------------
// grid (391, 2): y selects j-range [0,6) / [6,12) and the output partial buffer
// __launch_bounds__(256,2): R5's (256,3) forced VGPR 128->84 and spilled
// (FETCH 34->299MB, WRITE 27->194MB). LDS (51.2KB) caps at 3 blocks/CU anyway.
__global__ __launch_bounds__(256, 2) void fused_gemm_kernel(
        const unsigned short* __restrict__ xbf, const unsigned short* __restrict__ mean1,
        const unsigned short* __restrict__ WcatT, const float* __restrict__ b1e,
        const unsigned short* __restrict__ W2catT,
        float* __restrict__ pp0, float* __restrict__ pp1) {
    __shared__ __align__(16) unsigned short As[128 * 32];
    __shared__ __align__(16) unsigned short Bs[128 * 32];
    __shared__ __align__(16) unsigned short Ht[128 * 136];

    int m0 = blockIdx.x * 128;
    int jb = blockIdx.y * 6;
    float* pout = blockIdx.y ? pp1 : pp0;
    int tid = threadIdx.x;
    int lane = tid & 63, wid = tid >> 6;
    int wm = wid >> 1, wn = wid & 1;
    int quad = lane >> 4, l15 = lane & 15;

    f32x4 pacc[4][4] = {};

    for (int j = jb; j < jb + 6; ++j) {
        f32x4 hacc[4][4] = {};
        for (int kk = 0; kk < 256; kk += 32) {
#pragma unroll
            for (int ci = 0; ci < 2; ++ci) {
                int cb = ci * 256 + wid * 64;
                int chunk = cb + lane;
                int n = chunk >> 2, kc = chunk & 3;
                const unsigned short* g = (kk < 128)
                    ? xbf + (size_t)(m0 + n) * NF + kk + kc * 8
                    : mean1 + (size_t)(m0 + n) * NF + (kk - 128) + kc * 8;
                lds_dma16(g, &As[cb * 8]);
            }
#pragma unroll
            for (int ci = 0; ci < 2; ++ci) {
                int cb = ci * 256 + wid * 64;
                int chunk = cb + lane;
                int n = chunk >> 2, kc = chunk & 3;
                const unsigned short* g = WcatT + (size_t)(j * 128 + n) * 256 + kk + kc * 8;
                lds_dma16(g, &Bs[cb * 8]);
            }
            __syncthreads();
            bf16x8 a[4], b[4];
#pragma unroll
            for (int mi = 0; mi < 4; ++mi)
                a[mi] = *(const bf16x8*)(&As[(wm * 64 + mi * 16 + l15) * 32 + quad * 8]);
#pragma unroll
            for (int ni = 0; ni < 4; ++ni)
                b[ni] = *(const bf16x8*)(&Bs[(wn * 64 + ni * 16 + l15) * 32 + quad * 8]);
#pragma unroll
            for (int mi = 0; mi < 4; ++mi)
#pragma unroll
                for (int ni = 0; ni < 4; ++ni)
                    hacc[mi][ni] = __builtin_amdgcn_mfma_f32_16x16x32_bf16(a[mi], b[ni], hacc[mi][ni], 0, 0, 0);
            __syncthreads();
        }
#pragma unroll
        for (int ni = 0; ni < 4; ++ni) {
            int lc = wn * 64 + ni * 16 + l15;
            float bv = b1e[j * 128 + lc];
#pragma unroll
            for (int mi = 0; mi < 4; ++mi) {
#pragma unroll
                for (int r = 0; r < 4; ++r) {
                    int row = wm * 64 + mi * 16 + quad * 4 + r;
                    Ht[row * 136 + lc] = f2bf(fmaxf(hacc[mi][ni][r] + bv, 0.f));
                }
            }
        }
        __syncthreads();
#pragma unroll
        for (int kk2 = 0; kk2 < 128; kk2 += 32) {
            bf16x8 a2[4], b2[4];
#pragma unroll
            for (int mi = 0; mi < 4; ++mi)
                a2[mi] = *(const bf16x8*)(&Ht[(wm * 64 + mi * 16 + l15) * 136 + kk2 + quad * 8]);
#pragma unroll
            for (int ni = 0; ni < 4; ++ni)
                b2[ni] = *(const bf16x8*)(W2catT + (size_t)(wn * 64 + ni * 16 + l15) * NHIDP
                                          + j * 128 + kk2 + quad * 8);
#pragma unroll
            for (int mi = 0; mi < 4; ++mi)
#pragma unroll
                for (int ni = 0; ni < 4; ++ni)
                    pacc[mi][ni] = __builtin_amdgcn_mfma_f32_16x16x32_bf16(a2[mi], b2[ni], pacc[mi][ni], 0, 0, 0);
        }
        __syncthreads();
    }

#pragma unroll
    for (int ni = 0; ni < 4; ++ni) {
        int gc = wn * 64 + ni * 16 + l15;
#pragma unroll
        for (int mi = 0; mi < 4; ++mi) {
#pragma unroll
            for (int r = 0; r < 4; ++r) {
                int gr = m0 + wm * 64 + mi * 16 + quad * 4 + r;
                if (gr < RES0) pout[(size_t)gr * 128 + gc] = pacc[mi][ni][r];
            }
        }
    }
}

// ---------------- padd: pp0 += pp1 ------------------------------------------
__global__ __launch_bounds__(256) void padd_kernel(float* __restrict__ pp0,
                                                   const float* __restrict__ pp1) {
    size_t i = (size_t)blockIdx.x * 256 + threadIdx.x;
    f32x4 a = ((const f32x4*)pp0)[i];
    f32x4 b = ((const f32x4*)pp1)[i];
    ((f32x4*)pp0)[i] = a + b;
}

// ---------------- fused layer-2 aggregation + log_softmax --------------------
__global__ __launch_bounds__(64) void final_csr_kernel(
        const float* __restrict__ p, const int* __restrict__ csr,
        const u32* __restrict__ off, const u32* __restrict__ cnt,
        const float* __restrict__ b2, float* __restrict__ out) {
    int row = blockIdx.x;
    int c = threadIdx.x;
    u32 base = off[row], deg = cnt[row];
    float a0 = 0.f, a1 = 0.f, a2 = 0.f, a3 = 0.f;
    u32 e = 0;
    for (; e + 4 <= deg; e += 4) {
        int s0 = csr[base + e], s1 = csr[base + e + 1];
        int s2 = csr[base + e + 2], s3 = csr[base + e + 3];
        a0 += p[(size_t)s0 * 128 + c];
        a1 += p[(size_t)s1 * 128 + c];
        a2 += p[(size_t)s2 * 128 + c];
        a3 += p[(size_t)s3 * 128 + c];
    }
    for (; e < deg; ++e) a0 += p[(size_t)csr[base + e] * 128 + c];
    float mean = ((a0 + a1) + (a2 + a3)) / fmaxf((float)deg, 1.0f);
    float v = p[(size_t)row * 128 + 64 + c] + mean + b2[c];
    float m = v;
#pragma unroll
    for (int o = 32; o > 0; o >>= 1) m = fmaxf(m, __shfl_xor(m, o, 64));
    float ex = expf(v - m);
    float s = ex;
#pragma unroll
    for (int o = 32; o > 0; o >>= 1) s += __shfl_xor(s, o, 64);
    out[(size_t)row * 64 + c] = v - m - logf(s);
}

extern "C" void kernel_launch(void* const* d_in, const int* in_sizes, int n_in,
                              void* d_out, int out_size, void* d_ws, size_t ws_size,
                              hipStream_t stream) {
    const float* x   = (const float*)d_in[0];
    const float* W1r = (const float*)d_in[1];
    const float* W1n = (const float*)d_in[2];
    const float* b1  = (const float*)d_in[3];
    const float* W2r = (const float*)d_in[4];
    const float* W2n = (const float*)d_in[5];
    const float* b2  = (const float*)d_in[6];
    const int* es0 = (const int*)d_in[7];
    const int* et0 = (const int*)d_in[8];
    const int* es1 = (const int*)d_in[9];
    const int* et1 = (const int*)d_in[10];
    float* out = (float*)d_out;

    char* ws = (char*)d_ws;
    // --- region 0 [0, 25.6 MB): pp1 aliases CSR-phase temporaries (all dead
    //     before fused_gemm writes pp1) ---
    const size_t PPBYTES = (size_t)RES0 * 128 * 4;   // 25,600,000
    float* pp1 = (float*)ws;
    size_t o0 = 0;
    auto alloc0 = [&](size_t bytes) {
        void* ptr = ws + o0;
        o0 = (o0 + bytes + 255) & ~(size_t)255;
        return ptr;
    };
    u64* bkt1  = (u64*)alloc0((size_t)E0N * 8);        // 12.8 MB
    u64* bkt2  = (u64*)alloc0((size_t)E1N * 8);        //  4.0 MB
    int* csr1  = (int*)alloc0((size_t)E0N * 4);        //  6.4 MB
    u32* H1    = (u32*)alloc0((size_t)NCH0 * NB0 * 4);
    u32* base1 = (u32*)alloc0((size_t)NCH0 * NB0 * 4);
    u32* H2    = (u32*)alloc0((size_t)NCH1 * NB1 * 4);
    u32* base2 = (u32*)alloc0((size_t)NCH1 * NB1 * 4);
    u32* Bsum1 = (u32*)alloc0((size_t)NB0 * 4);
    u32* Bsum2 = (u32*)alloc0((size_t)NB1 * 4);
    u32* boff1 = (u32*)alloc0((size_t)NB0 * 4);
    u32* boff2 = (u32*)alloc0((size_t)NB1 * 4);
    u32* off1  = (u32*)alloc0((size_t)RES0 * 4);
    u32* cnt1  = (u32*)alloc0((size_t)RES0 * 4);
    // (o0 ≈ 24.3 MB < 25.6 MB — fits under pp1)

    // --- live region, starts after pp1 ---
    size_t off_ = PPBYTES;                              // 25,600,000 (256-aligned)
    auto alloc = [&](size_t bytes) {
        void* ptr = ws + off_;
        off_ = (off_ + bytes + 255) & ~(size_t)255;
        return ptr;
    };
    int* csr2  = (int*)alloc((size_t)E1N * 4);
    u32* off2  = (u32*)alloc((size_t)RES1 * 4);
    u32* cnt2  = (u32*)alloc((size_t)RES1 * 4);
    unsigned short* xbf    = (unsigned short*)alloc((size_t)NSRC * NF * 2);
    unsigned short* mean1  = (unsigned short*)alloc((size_t)(RES0 + 128) * NF * 2);
    unsigned short* WcatT  = (unsigned short*)alloc((size_t)NHIDP * 256 * 2);
    unsigned short* W2catT = (unsigned short*)alloc((size_t)128 * NHIDP * 2);
    float*          b1e    = (float*)alloc((size_t)NHIDP * 4);
    float*          pp0    = (float*)alloc(PPBYTES);

    prep_kernel<<<(256 * NHIDP + 128 * NHIDP + NHIDP + 255) / 256, 256, 0, stream>>>(
        W1r, W1n, b1, W2r, W2n, WcatT, W2catT, b1e);

    copyx_kernel<<<(NSRC * NF) / (256 * 8), 256, 0, stream>>>(x, xbf);

    // bucket counting sort -> CSR (+ per-target off/cnt from p2)
    p1a_kernel<<<NCH0, 256, 0, stream>>>(et0, E0N, NB0, H1);
    p1a_kernel<<<NCH1, 256, 0, stream>>>(et1, E1N, NB1, H2);
    bscan_kernel<<<NB0, 512, 0, stream>>>(H1, NCH0, NB0, base1, Bsum1);
    bscan_kernel<<<NB1, 512, 0, stream>>>(H2, NCH1, NB1, base2, Bsum2);
    boff_kernel<<<2, 256, 0, stream>>>(Bsum1, boff1, NB0, Bsum2, boff2, NB1);
    p1b_kernel<<<NCH0, 256, 0, stream>>>(es0, et0, E0N, NB0, base1, boff1, bkt1);
    p1b_kernel<<<NCH1, 256, 0, stream>>>(es1, et1, E1N, NB1, base2, boff2, bkt2);
    p2_kernel<<<NB0, 1024, 0, stream>>>(bkt1, boff1, NB0, RES0, E0N, csr1, off1, cnt1);
    p2_kernel<<<NB1, 1024, 0, stream>>>(bkt2, boff2, NB1, RES1, E1N, csr2, off2, cnt2);

    agg1_csr_kernel<<<(RES0 + 3) / 4, 256, 0, stream>>>(
        (const u32*)xbf, csr1, off1, cnt1, (u32*)mean1);

    fused_gemm_kernel<<<dim3((RES0 + 127) / 128, 2), 256, 0, stream>>>(
        xbf, mean1, WcatT, b1e, W2catT, pp0, pp1);

    padd_kernel<<<(RES0 * 128 / 4 + 255) / 256, 256, 0, stream>>>(pp0, pp1);

    final_csr_kernel<<<RES1, 64, 0, stream>>>(pp0, csr2, off2, cnt2, b2, out);
}

// Round 7
// 460.760 us; speedup vs baseline: 2.7461x; 1.0842x over previous
//
#include <hip/hip_runtime.h>
#include <hip/hip_bf16.h>
#include <cstdint>
#include <cstddef>

// Problem constants (from reference)
#define NSRC   200000
#define NF     128
#define NHID   1500
#define NHIDP  1536     // padded hidden dim (multiple of 128)
#define NCLS   64
#define E0N    1600000
#define E1N    500000
#define RES0   50000
#define RES1   10000

// CSR bucket-sort parameters
#define CH     4096                       // edges per chunk
#define NCH0   ((E0N + CH - 1) / CH)      // 391
#define NCH1   ((E1N + CH - 1) / CH)      // 123
#define NB0    ((RES0 + 255) / 256)      // 196 buckets of 256 targets
#define NB1    ((RES1 + 255) / 256)      // 40

#define PREP_BLOCKS  ((256 * NHIDP + 128 * NHIDP + NHIDP + 255) / 256)   // 2310
#define COPYX_BLOCKS ((NSRC * NF) / (256 * 8))                           // 12500

typedef __bf16 bf16x8 __attribute__((ext_vector_type(8)));
typedef float  f32x4  __attribute__((ext_vector_type(4)));
typedef unsigned short u16x8 __attribute__((ext_vector_type(8)));
typedef unsigned int u32;
typedef unsigned long long u64;

__device__ __forceinline__ unsigned short f2bf(float f) {
    union { float f; unsigned u; } v; v.f = f;
    unsigned r = v.u + 0x7fffu + ((v.u >> 16) & 1u);   // RNE
    return (unsigned short)(r >> 16);
}

// async 16B global -> LDS DMA (dest = wave-uniform lds base + lane*16)
__device__ __forceinline__ void lds_dma16(const void* g, void* lds) {
    __builtin_amdgcn_global_load_lds(
        (const __attribute__((address_space(1))) unsigned int*)g,
        (__attribute__((address_space(3))) unsigned int*)lds, 16, 0, 0);
}

// ---------------- setup: weight prep + x->bf16 copy (merged) -----------------
__global__ __launch_bounds__(256) void setup_kernel(
        const float* __restrict__ x, unsigned short* __restrict__ xbf,
        const float* __restrict__ W1r, const float* __restrict__ W1n,
        const float* __restrict__ b1,
        const float* __restrict__ W2r, const float* __restrict__ W2n,
        unsigned short* __restrict__ WcatT, unsigned short* __restrict__ W2catT,
        float* __restrict__ b1e) {
    int bid = blockIdx.x;
    if (bid < PREP_BLOCKS) {
        int id = bid * 256 + threadIdx.x;
        if (id < 256 * NHIDP) {
            int n = id >> 8, k = id & 255;
            float v = 0.f;
            if (n < NHID) v = (k < NF) ? W1r[k * NHID + n] : W1n[(k - NF) * NHID + n];
            WcatT[n * 256 + k] = f2bf(v);
        } else {
            int id2 = id - 256 * NHIDP;
            if (id2 < 128 * NHIDP) {
                int n = id2 / NHIDP, k = id2 % NHIDP;
                float v = 0.f;
                if (k < NHID) v = (n < 64) ? W2n[k * 64 + n] : W2r[k * 64 + (n - 64)];
                W2catT[n * NHIDP + k] = f2bf(v);
            } else {
                int c = id2 - 128 * NHIDP;
                if (c < NHIDP) b1e[c] = (c < NHID) ? b1[c] : 0.f;
            }
        }
    } else {
        size_t i = ((size_t)(bid - PREP_BLOCKS) * 256 + threadIdx.x) * 8;
        const float4* s = (const float4*)(x + i);
        float4 a = s[0], b = s[1];
        u16x8 o;
        o[0] = f2bf(a.x); o[1] = f2bf(a.y); o[2] = f2bf(a.z); o[3] = f2bf(a.w);
        o[4] = f2bf(b.x); o[5] = f2bf(b.y); o[6] = f2bf(b.z); o[7] = f2bf(b.w);
        *(u16x8*)(xbf + i) = o;
    }
}

// ---------------- CSR phase 1a: per-chunk bucket histogram (both graphs) -----
__device__ __forceinline__ void p1a_body(const int* __restrict__ tgt, int n,
                                         int nb, u32* __restrict__ H, int c) {
    __shared__ u32 lhist[256];
    int tid = threadIdx.x;
    lhist[tid] = 0;
    __syncthreads();
#pragma unroll
    for (int it = 0; it < CH / 256; ++it) {
        int i = c * CH + it * 256 + tid;
        if (i < n) atomicAdd(&lhist[((u32)tgt[i]) >> 8], 1u);
    }
    __syncthreads();
    if (tid < nb) H[c * nb + tid] = lhist[tid];
}

__global__ __launch_bounds__(256) void p1a_both_kernel(
        const int* __restrict__ t0, const int* __restrict__ t1,
        u32* __restrict__ H1, u32* __restrict__ H2) {
    int b = blockIdx.x;
    if (b < NCH0) p1a_body(t0, E0N, NB0, H1, b);
    else          p1a_body(t1, E1N, NB1, H2, b - NCH0);
}

// ---------------- bscan: per-bucket exclusive scan over chunks + totals ------
__device__ __forceinline__ void bscan_body(const u32* __restrict__ H,
                                           int nch, int nb, int b,
                                           u32* __restrict__ base_rel,
                                           u32* __restrict__ Bsum) {
    __shared__ u32 part[512];
    int t = threadIdx.x;
    part[t] = (t < nch) ? H[t * nb + b] : 0u;
    __syncthreads();
    for (int d = 1; d < 512; d <<= 1) {
        u32 v = part[t];
        u32 add = (t >= d) ? part[t - d] : 0u;
        __syncthreads();
        part[t] = v + add;
        __syncthreads();
    }
    if (t < nch) base_rel[t * nb + b] = (t == 0) ? 0u : part[t - 1];
    if (t == 0) Bsum[b] = part[nch - 1];
}

__global__ __launch_bounds__(512) void bscan_both_kernel(
        const u32* __restrict__ H1, u32* __restrict__ base1, u32* __restrict__ Bsum1,
        const u32* __restrict__ H2, u32* __restrict__ base2, u32* __restrict__ Bsum2) {
    int b = blockIdx.x;
    if (b < NB0) bscan_body(H1, NCH0, NB0, b, base1, Bsum1);
    else         bscan_body(H2, NCH1, NB1, b - NB0, base2, Bsum2);
}

// ---------------- boff: exclusive scan over bucket totals (both graphs) ------
__global__ __launch_bounds__(256) void boff_kernel(const u32* __restrict__ Bsum1,
                                                   u32* __restrict__ boff1, int nb1,
                                                   const u32* __restrict__ Bsum2,
                                                   u32* __restrict__ boff2, int nb2) {
    const u32* B = blockIdx.x ? Bsum2 : Bsum1;
    u32* O = blockIdx.x ? boff2 : boff1;
    int nb = blockIdx.x ? nb2 : nb1;
    __shared__ u32 part[256];
    int t = threadIdx.x;
    part[t] = (t < nb) ? B[t] : 0u;
    __syncthreads();
    for (int d = 1; d < 256; d <<= 1) {
        u32 v = part[t];
        u32 add = (t >= d) ? part[t - d] : 0u;
        __syncthreads();
        part[t] = v + add;
        __syncthreads();
    }
    if (t < nb) O[t] = (t == 0) ? 0u : part[t - 1];
}

// ---------------- phase 1b: bucket-grouped scatter of (tgt,src) pairs --------
__device__ __forceinline__ void p1b_body(const int* __restrict__ src,
                                         const int* __restrict__ tgt, int n,
                                         int nb, const u32* __restrict__ base_rel,
                                         const u32* __restrict__ boff,
                                         u64* __restrict__ bucketed, int c) {
    __shared__ u32 lcur[256];
    __shared__ u32 lbase[256];
    int tid = threadIdx.x;
    lcur[tid] = 0;
    if (tid < nb) lbase[tid] = base_rel[c * nb + tid] + boff[tid];
    __syncthreads();
#pragma unroll
    for (int it = 0; it < CH / 256; ++it) {
        int i = c * CH + it * 256 + tid;
        if (i < n) {
            u32 t = (u32)tgt[i];
            u32 s = (u32)src[i];
            u32 b = t >> 8;
            u32 r = atomicAdd(&lcur[b], 1u);
            bucketed[lbase[b] + r] = ((u64)t << 32) | (u64)s;
        }
    }
}

__global__ __launch_bounds__(256) void p1b_both_kernel(
        const int* __restrict__ s0, const int* __restrict__ t0,
        const u32* __restrict__ base1, const u32* __restrict__ boff1,
        u64* __restrict__ bkt1,
        const int* __restrict__ s1, const int* __restrict__ t1,
        const u32* __restrict__ base2, const u32* __restrict__ boff2,
        u64* __restrict__ bkt2) {
    int b = blockIdx.x;
    if (b < NCH0) p1b_body(s0, t0, E0N, NB0, base1, boff1, bkt1, b);
    else          p1b_body(s1, t1, E1N, NB1, base2, boff2, bkt2, b - NCH0);
}

// ---------------- phase 2: per-bucket sort -> CSR + per-target off/cnt -------
__device__ __forceinline__ void p2_body(const u64* __restrict__ bucketed,
                                        const u32* __restrict__ boff,
                                        int nb, int res, int etot,
                                        int* __restrict__ csr,
                                        u32* __restrict__ off_out,
                                        u32* __restrict__ cnt_out, int b) {
    __shared__ u32 lhist[256];
    __shared__ u32 part[256];
    __shared__ u32 cur[256];
    int tid = threadIdx.x;
    u32 start = boff[b];
    u32 end = (b == nb - 1) ? (u32)etot : boff[b + 1];
    u32 count = end - start;
    if (tid < 256) lhist[tid] = 0;
    __syncthreads();
    for (u32 i = tid; i < count; i += 1024) {
        u32 t = (u32)(bucketed[start + i] >> 32);
        atomicAdd(&lhist[t & 255u], 1u);
    }
    __syncthreads();
    if (tid < 256) part[tid] = lhist[tid];
    __syncthreads();
    for (int d = 1; d < 256; d <<= 1) {
        u32 v = (tid < 256) ? part[tid] : 0u;
        u32 add = (tid >= d && tid < 256) ? part[tid - d] : 0u;
        __syncthreads();
        if (tid < 256) part[tid] = v + add;
        __syncthreads();
    }
    if (tid < 256) {
        u32 excl = (tid == 0) ? 0u : part[tid - 1];
        cur[tid] = excl;
        int tg = (b << 8) + tid;
        if (tg < res) {
            off_out[tg] = start + excl;
            cnt_out[tg] = lhist[tid];
        }
    }
    __syncthreads();
    for (u32 i = tid; i < count; i += 1024) {
        u64 pr = bucketed[start + i];
        u32 lt = ((u32)(pr >> 32)) & 255u;
        u32 r = atomicAdd(&cur[lt], 1u);
        csr[start + r] = (int)(u32)pr;
    }
}

__global__ __launch_bounds__(1024) void p2_both_kernel(
        const u64* __restrict__ bkt1, const u32* __restrict__ boff1,
        int* __restrict__ csr1, u32* __restrict__ off1, u32* __restrict__ cnt1,
        const u64* __restrict__ bkt2, const u32* __restrict__ boff2,
        int* __restrict__ csr2, u32* __restrict__ off2, u32* __restrict__ cnt2) {
    int b = blockIdx.x;
    if (b < NB0) p2_body(bkt1, boff1, NB0, RES0, E0N, csr1, off1, cnt1, b);
    else         p2_body(bkt2, boff2, NB1, RES1, E1N, csr2, off2, cnt2, b - NB0);
}

// ---------------- layer-1 mean aggregation: 1 wave/row, u32 gathers ----------
__global__ __launch_bounds__(256) void agg1_csr_kernel(
        const u32* __restrict__ xb32, const int* __restrict__ csr,
        const u32* __restrict__ off, const u32* __restrict__ cnt,
        u32* __restrict__ mean1_32) {
    int row = blockIdx.x * 4 + (threadIdx.x >> 6);
    int lane = threadIdx.x & 63;
    if (row >= RES0) return;
    u32 base = off[row], deg = cnt[row];
    float x0 = 0.f, y0 = 0.f, x1 = 0.f, y1 = 0.f;
    float x2 = 0.f, y2 = 0.f, x3 = 0.f, y3 = 0.f;
    u32 e = 0;
    for (; e + 4 <= deg; e += 4) {
        int s0 = csr[base + e], s1 = csr[base + e + 1];
        int s2 = csr[base + e + 2], s3 = csr[base + e + 3];
        u32 w0 = xb32[(size_t)s0 * 64 + lane];
        u32 w1 = xb32[(size_t)s1 * 64 + lane];
        u32 w2 = xb32[(size_t)s2 * 64 + lane];
        u32 w3 = xb32[(size_t)s3 * 64 + lane];
        union { u32 u; float f; } a, b;
        a.u = w0 << 16; b.u = w0 & 0xffff0000u; x0 += a.f; y0 += b.f;
        a.u = w1 << 16; b.u = w1 & 0xffff0000u; x1 += a.f; y1 += b.f;
        a.u = w2 << 16; b.u = w2 & 0xffff0000u; x2 += a.f; y2 += b.f;
        a.u = w3 << 16; b.u = w3 & 0xffff0000u; x3 += a.f; y3 += b.f;
    }
    for (; e < deg; ++e) {
        u32 w = xb32[(size_t)csr[base + e] * 64 + lane];
        union { u32 u; float f; } a, b;
        a.u = w << 16; b.u = w & 0xffff0000u; x0 += a.f; y0 += b.f;
    }
    float inv = 1.0f / fmaxf((float)deg, 1.0f);
    float mx = ((x0 + x1) + (x2 + x3)) * inv;
    float my = ((y0 + y1) + (y2 + y3)) * inv;
    mean1_32[(size_t)row * 64 + lane] = (u32)f2bf(mx) | ((u32)f2bf(my) << 16);
}

// ---------------- fused GEMM: BK=64 (split k-half buffers), j-split grid -----
// grid (391, 2). 32 MFMAs per barrier pair (was 16); barriers/j 18 -> 10.
// LDS 67.6 KB <= 80 KB keeps 2 blocks/CU; (256,2) avoids the R5 spill cliff.
__global__ __launch_bounds__(256, 2) void fused_gemm_kernel(
        const unsigned short* __restrict__ xbf, const unsigned short* __restrict__ mean1,
        const unsigned short* __restrict__ WcatT, const float* __restrict__ b1e,
        const unsigned short* __restrict__ W2catT,
        float* __restrict__ pp0, float* __restrict__ pp1) {
    __shared__ __align__(16) unsigned short As0[128 * 32];
    __shared__ __align__(16) unsigned short As1[128 * 32];
    __shared__ __align__(16) unsigned short Bs0[128 * 32];
    __shared__ __align__(16) unsigned short Bs1[128 * 32];
    __shared__ __align__(16) unsigned short Ht[128 * 136];

    int m0 = blockIdx.x * 128;
    int jb = blockIdx.y * 6;
    float* pout = blockIdx.y ? pp1 : pp0;
    int tid = threadIdx.x;
    int lane = tid & 63, wid = tid >> 6;
    int wm = wid >> 1, wn = wid & 1;
    int quad = lane >> 4, l15 = lane & 15;

    f32x4 pacc[4][4] = {};

    for (int j = jb; j < jb + 6; ++j) {
        f32x4 hacc[4][4] = {};
        for (int kk = 0; kk < 256; kk += 64) {
            // stage A k-halves [kk,kk+32) -> As0, [kk+32,kk+64) -> As1
#pragma unroll
            for (int kh = 0; kh < 2; ++kh) {
                int ksel = kk + kh * 32;
                const unsigned short* src = (ksel < 128)
                    ? xbf + (size_t)m0 * NF + ksel
                    : mean1 + (size_t)m0 * NF + (ksel - 128);
                unsigned short* dst = kh ? As1 : As0;
#pragma unroll
                for (int ci = 0; ci < 2; ++ci) {
                    int cb = ci * 256 + wid * 64;
                    int chunk = cb + lane;
                    int n = chunk >> 2, kc = chunk & 3;
                    lds_dma16(src + (size_t)n * NF + kc * 8, &dst[cb * 8]);
                }
            }
            // stage B k-halves
#pragma unroll
            for (int kh = 0; kh < 2; ++kh) {
                int ksel = kk + kh * 32;
                const unsigned short* src = WcatT + (size_t)(j * 128) * 256 + ksel;
                unsigned short* dst = kh ? Bs1 : Bs0;
#pragma unroll
                for (int ci = 0; ci < 2; ++ci) {
                    int cb = ci * 256 + wid * 64;
                    int chunk = cb + lane;
                    int n = chunk >> 2, kc = chunk & 3;
                    lds_dma16(src + (size_t)n * 256 + kc * 8, &dst[cb * 8]);
                }
            }
            __syncthreads();
#pragma unroll
            for (int kh = 0; kh < 2; ++kh) {
                const unsigned short* Asb = kh ? As1 : As0;
                const unsigned short* Bsb = kh ? Bs1 : Bs0;
                bf16x8 a[4], b[4];
#pragma unroll
                for (int mi = 0; mi < 4; ++mi)
                    a[mi] = *(const bf16x8*)(&Asb[(wm * 64 + mi * 16 + l15) * 32 + quad * 8]);
#pragma unroll
                for (int ni = 0; ni < 4; ++ni)
                    b[ni] = *(const bf16x8*)(&Bsb[(wn * 64 + ni * 16 + l15) * 32 + quad * 8]);
#pragma unroll
                for (int mi = 0; mi < 4; ++mi)
#pragma unroll
                    for (int ni = 0; ni < 4; ++ni)
                        hacc[mi][ni] = __builtin_amdgcn_mfma_f32_16x16x32_bf16(a[mi], b[ni], hacc[mi][ni], 0, 0, 0);
            }
            __syncthreads();
        }
        // epilogue 1: bias + relu -> bf16 -> Ht (C-layout -> [m][k])
#pragma unroll
        for (int ni = 0; ni < 4; ++ni) {
            int lc = wn * 64 + ni * 16 + l15;
            float bv = b1e[j * 128 + lc];
#pragma unroll
            for (int mi = 0; mi < 4; ++mi) {
#pragma unroll
                for (int r = 0; r < 4; ++r) {
                    int row = wm * 64 + mi * 16 + quad * 4 + r;
                    Ht[row * 136 + lc] = f2bf(fmaxf(hacc[mi][ni][r] + bv, 0.f));
                }
            }
        }
        __syncthreads();
        // stage 2: pacc += Ht(128x128) @ W2cat_j(128x128)
#pragma unroll
        for (int kk2 = 0; kk2 < 128; kk2 += 32) {
            bf16x8 a2[4], b2[4];
#pragma unroll
            for (int mi = 0; mi < 4; ++mi)
                a2[mi] = *(const bf16x8*)(&Ht[(wm * 64 + mi * 16 + l15) * 136 + kk2 + quad * 8]);
#pragma unroll
            for (int ni = 0; ni < 4; ++ni)
                b2[ni] = *(const bf16x8*)(W2catT + (size_t)(wn * 64 + ni * 16 + l15) * NHIDP
                                          + j * 128 + kk2 + quad * 8);
#pragma unroll
            for (int mi = 0; mi < 4; ++mi)
#pragma unroll
                for (int ni = 0; ni < 4; ++ni)
                    pacc[mi][ni] = __builtin_amdgcn_mfma_f32_16x16x32_bf16(a2[mi], b2[ni], pacc[mi][ni], 0, 0, 0);
        }
        __syncthreads();   // protect Ht before next j overwrites
    }

#pragma unroll
    for (int ni = 0; ni < 4; ++ni) {
        int gc = wn * 64 + ni * 16 + l15;
#pragma unroll
        for (int mi = 0; mi < 4; ++mi) {
#pragma unroll
            for (int r = 0; r < 4; ++r) {
                int gr = m0 + wm * 64 + mi * 16 + quad * 4 + r;
                if (gr < RES0) pout[(size_t)gr * 128 + gc] = pacc[mi][ni][r];
            }
        }
    }
}

// ---------------- padd: pp0 += pp1 ------------------------------------------
__global__ __launch_bounds__(256) void padd_kernel(float* __restrict__ pp0,
                                                   const float* __restrict__ pp1) {
    size_t i = (size_t)blockIdx.x * 256 + threadIdx.x;
    f32x4 a = ((const f32x4*)pp0)[i];
    f32x4 b = ((const f32x4*)pp1)[i];
    ((f32x4*)pp0)[i] = a + b;
}

// ---------------- fused layer-2 aggregation + log_softmax --------------------
__global__ __launch_bounds__(64) void final_csr_kernel(
        const float* __restrict__ p, const int* __restrict__ csr,
        const u32* __restrict__ off, const u32* __restrict__ cnt,
        const float* __restrict__ b2, float* __restrict__ out) {
    int row = blockIdx.x;
    int c = threadIdx.x;
    u32 base = off[row], deg = cnt[row];
    float a0 = 0.f, a1 = 0.f, a2 = 0.f, a3 = 0.f;
    u32 e = 0;
    for (; e + 4 <= deg; e += 4) {
        int s0 = csr[base + e], s1 = csr[base + e + 1];
        int s2 = csr[base + e + 2], s3 = csr[base + e + 3];
        a0 += p[(size_t)s0 * 128 + c];
        a1 += p[(size_t)s1 * 128 + c];
        a2 += p[(size_t)s2 * 128 + c];
        a3 += p[(size_t)s3 * 128 + c];
    }
    for (; e < deg; ++e) a0 += p[(size_t)csr[base + e] * 128 + c];
    float mean = ((a0 + a1) + (a2 + a3)) / fmaxf((float)deg, 1.0f);
    float v = p[(size_t)row * 128 + 64 + c] + mean + b2[c];
    float m = v;
#pragma unroll
    for (int o = 32; o > 0; o >>= 1) m = fmaxf(m, __shfl_xor(m, o, 64));
    float ex = expf(v - m);
    float s = ex;
#pragma unroll
    for (int o = 32; o > 0; o >>= 1) s += __shfl_xor(s, o, 64);
    out[(size_t)row * 64 + c] = v - m - logf(s);
}

extern "C" void kernel_launch(void* const* d_in, const int* in_sizes, int n_in,
                              void* d_out, int out_size, void* d_ws, size_t ws_size,
                              hipStream_t stream) {
    const float* x   = (const float*)d_in[0];
    const float* W1r = (const float*)d_in[1];
    const float* W1n = (const float*)d_in[2];
    const float* b1  = (const float*)d_in[3];
    const float* W2r = (const float*)d_in[4];
    const float* W2n = (const float*)d_in[5];
    const float* b2  = (const float*)d_in[6];
    const int* es0 = (const int*)d_in[7];
    const int* et0 = (const int*)d_in[8];
    const int* es1 = (const int*)d_in[9];
    const int* et1 = (const int*)d_in[10];
    float* out = (float*)d_out;

    char* ws = (char*)d_ws;
    // --- region 0 [0, 25.6 MB): pp1 aliases CSR-phase temporaries (all dead
    //     before fused_gemm writes pp1) ---
    const size_t PPBYTES = (size_t)RES0 * 128 * 4;   // 25,600,000
    float* pp1 = (float*)ws;
    size_t o0 = 0;
    auto alloc0 = [&](size_t bytes) {
        void* ptr = ws + o0;
        o0 = (o0 + bytes + 255) & ~(size_t)255;
        return ptr;
    };
    u64* bkt1  = (u64*)alloc0((size_t)E0N * 8);        // 12.8 MB
    u64* bkt2  = (u64*)alloc0((size_t)E1N * 8);        //  4.0 MB
    int* csr1  = (int*)alloc0((size_t)E0N * 4);        //  6.4 MB
    u32* H1    = (u32*)alloc0((size_t)NCH0 * NB0 * 4);
    u32* base1 = (u32*)alloc0((size_t)NCH0 * NB0 * 4);
    u32* H2    = (u32*)alloc0((size_t)NCH1 * NB1 * 4);
    u32* base2 = (u32*)alloc0((size_t)NCH1 * NB1 * 4);
    u32* Bsum1 = (u32*)alloc0((size_t)NB0 * 4);
    u32* Bsum2 = (u32*)alloc0((size_t)NB1 * 4);
    u32* boff1 = (u32*)alloc0((size_t)NB0 * 4);
    u32* boff2 = (u32*)alloc0((size_t)NB1 * 4);
    u32* off1  = (u32*)alloc0((size_t)RES0 * 4);
    u32* cnt1  = (u32*)alloc0((size_t)RES0 * 4);
    // (o0 ≈ 24.3 MB < 25.6 MB — fits under pp1)

    // --- live region, starts after pp1 ---
    size_t off_ = PPBYTES;
    auto alloc = [&](size_t bytes) {
        void* ptr = ws + off_;
        off_ = (off_ + bytes + 255) & ~(size_t)255;
        return ptr;
    };
    int* csr2  = (int*)alloc((size_t)E1N * 4);
    u32* off2  = (u32*)alloc((size_t)RES1 * 4);
    u32* cnt2  = (u32*)alloc((size_t)RES1 * 4);
    unsigned short* xbf    = (unsigned short*)alloc((size_t)NSRC * NF * 2);
    unsigned short* mean1  = (unsigned short*)alloc((size_t)(RES0 + 128) * NF * 2);
    unsigned short* WcatT  = (unsigned short*)alloc((size_t)NHIDP * 256 * 2);
    unsigned short* W2catT = (unsigned short*)alloc((size_t)128 * NHIDP * 2);
    float*          b1e    = (float*)alloc((size_t)NHIDP * 4);
    float*          pp0    = (float*)alloc(PPBYTES);

    setup_kernel<<<PREP_BLOCKS + COPYX_BLOCKS, 256, 0, stream>>>(
        x, xbf, W1r, W1n, b1, W2r, W2n, WcatT, W2catT, b1e);

    p1a_both_kernel<<<NCH0 + NCH1, 256, 0, stream>>>(et0, et1, H1, H2);
    bscan_both_kernel<<<NB0 + NB1, 512, 0, stream>>>(H1, base1, Bsum1, H2, base2, Bsum2);
    boff_kernel<<<2, 256, 0, stream>>>(Bsum1, boff1, NB0, Bsum2, boff2, NB1);
    p1b_both_kernel<<<NCH0 + NCH1, 256, 0, stream>>>(
        es0, et0, base1, boff1, bkt1, es1, et1, base2, boff2, bkt2);
    p2_both_kernel<<<NB0 + NB1, 1024, 0, stream>>>(
        bkt1, boff1, csr1, off1, cnt1, bkt2, boff2, csr2, off2, cnt2);

    agg1_csr_kernel<<<(RES0 + 3) / 4, 256, 0, stream>>>(
        (const u32*)xbf, csr1, off1, cnt1, (u32*)mean1);

    fused_gemm_kernel<<<dim3((RES0 + 127) / 128, 2), 256, 0, stream>>>(
        xbf, mean1, WcatT, b1e, W2catT, pp0, pp1);

    padd_kernel<<<(RES0 * 128 / 4 + 255) / 256, 256, 0, stream>>>(pp0, pp1);

    final_csr_kernel<<<RES1, 64, 0, stream>>>(pp0, csr2, off2, cnt2, b2, out);
}